// Round 6
// baseline (418.224 us; speedup 1.0000x reference)
//
#include <hip/hip_runtime.h>
#include <cstdint>
#include <cstddef>

#define D 128

typedef __attribute__((ext_vector_type(8))) short bf16x8;
typedef __attribute__((ext_vector_type(4))) float f32x4;
typedef __attribute__((ext_vector_type(8))) _Float16 f16x8;

__device__ __forceinline__ unsigned short f2bf(float f) {
  unsigned int u = __float_as_uint(f);
  unsigned int r = u + 0x7FFFu + ((u >> 16) & 1u);
  return (unsigned short)(r >> 16);
}
__device__ __forceinline__ float bf2f(unsigned short h) {
  return __uint_as_float((unsigned int)h << 16);
}

// ---------------- weight packing (all 12 matrices, one launch) ----------------
// slot m: hi at Wp[m*32768 + r], lo at Wp[m*32768 + 16384 + r]
// r = ((jt*4+ks)*64+lane)*8 + b  ->  W[(ks*32+(lane>>4)*8+b)*128 + jt*16+(lane&15)]
struct WPtrs { const float* w[12]; };

__global__ __launch_bounds__(256) void pack_all_kernel(WPtrs P, unsigned short* __restrict__ Wp) {
  int tid = blockIdx.x * blockDim.x + threadIdx.x;  // 0..196607
  int m = tid >> 14;
  int r = tid & 16383;
  int b = r & 7, lane = (r >> 3) & 63, ks = (r >> 9) & 3, jt = r >> 11;
  int k = ks * 32 + ((lane >> 4) << 3) + b;
  int j = jt * 16 + (lane & 15);
  float w = P.w[m][k * 128 + j];
  unsigned short h = f2bf(w);
  Wp[m * 32768 + r] = h;
  Wp[m * 32768 + 16384 + r] = f2bf(w - bf2f(h));
}

// ---------------- CSR build (concatenated: type0=[0,N), type1=[N,2N)) ----------------
__global__ void count_kernel(const int* __restrict__ d0, const int* __restrict__ d1,
                             int* __restrict__ cnt, int E, int N) {
  int e = blockIdx.x * blockDim.x + threadIdx.x;
  if (e < E) {
    atomicAdd(&cnt[d0[e]], 1);
    atomicAdd(&cnt[N + d1[e]], 1);
  }
}

__global__ __launch_bounds__(256) void scan_part_kernel(const int* __restrict__ cnt,
                                                        int* __restrict__ off,
                                                        int* __restrict__ bsum, int n2) {
  __shared__ int sh[256];
  int t = threadIdx.x;
  int i0 = blockIdx.x * 512 + 2 * t;
  int a0 = (i0 < n2) ? cnt[i0] : 0;
  int a1 = (i0 + 1 < n2) ? cnt[i0 + 1] : 0;
  int s = a0 + a1;
  sh[t] = s;
  __syncthreads();
  for (int d = 1; d < 256; d <<= 1) {
    int v = (t >= d) ? sh[t - d] : 0;
    __syncthreads();
    sh[t] += v;
    __syncthreads();
  }
  int p = sh[t] - s;
  if (i0 < n2) off[i0] = p;
  if (i0 + 1 < n2) off[i0 + 1] = p + a0;
  if (t == 255) bsum[blockIdx.x] = sh[255];
}

__global__ __launch_bounds__(256) void scan_bsum_kernel(int* __restrict__ bsum, int nb,
                                                        int* __restrict__ off_total) {
  __shared__ int sh[256];
  int t = threadIdx.x;
  int s = (t < nb) ? bsum[t] : 0;
  sh[t] = s;
  __syncthreads();
  for (int d = 1; d < 256; d <<= 1) {
    int v = (t >= d) ? sh[t - d] : 0;
    __syncthreads();
    sh[t] += v;
    __syncthreads();
  }
  if (t < nb) bsum[t] = sh[t] - s;
  if (t == 255) *off_total = sh[255];
}

__global__ __launch_bounds__(256) void scan_add_kernel(int* __restrict__ off,
                                                       const int* __restrict__ bsum,
                                                       int* __restrict__ cnt,
                                                       float* __restrict__ dinv, int n2) {
  int add = bsum[blockIdx.x];
  int base = blockIdx.x * 512;
#pragma unroll
  for (int u = 0; u < 2; u++) {
    int i = base + threadIdx.x + u * 256;
    if (i < n2) {
      off[i] += add;
      dinv[i] = rsqrtf((float)cnt[i] + 1.0f);
      cnt[i] = 0;
    }
  }
}

__global__ void fill_kernel(const int* __restrict__ ei0, const int* __restrict__ ei1,
                            const int* __restrict__ off, int* __restrict__ cnt,
                            int* __restrict__ csr, int E, int N) {
  int e = blockIdx.x * blockDim.x + threadIdx.x;
  if (e < E) {
    int s = ei0[e], d = ei0[E + e];
    int p = atomicAdd(&cnt[d], 1);
    csr[off[d] + p] = s;
    s = ei1[e]; d = ei1[E + e];
    p = atomicAdd(&cnt[N + d], 1);
    csr[off[N + d] + p] = s;
  }
}

// ---------------- split helpers ----------------
__device__ __forceinline__ void split8(const float vv[8], bf16x8& hh, bf16x8& hl) {
#pragma unroll
  for (int c = 0; c < 8; c++) {
    unsigned short h = f2bf(vv[c]);
    hh[c] = (short)h;
    hl[c] = (short)f2bf(vv[c] - bf2f(h));
  }
}

// ---------------- dual GCN matmul (operand-swapped, split precision) ----------------
template <int BN>
__global__ __launch_bounds__(256) void mm_dual(
    const unsigned short* __restrict__ Wp, const float* __restrict__ Af,
    const float* __restrict__ stats, const float* __restrict__ g0,
    const float* __restrict__ bt0, const float* __restrict__ dinv,
    _Float16* __restrict__ tab0, _Float16* __restrict__ tab1,
    int n, int N, float invn) {
  __shared__ float bnsc[128], bnsh[128];
  if (BN) {
    int t = threadIdx.x;
    if (t < 128) {
      float s = 0.f, q = 0.f;
#pragma unroll
      for (int r = 0; r < 8; r++) { s += stats[r * 128 + t]; q += stats[1024 + r * 128 + t]; }
      float mu = s * invn, var = q * invn - mu * mu;
      float sc = g0[t] * rsqrtf(var + 1e-5f);
      bnsc[t] = sc; bnsh[t] = bt0[t] - mu * sc;
    }
    __syncthreads();
  }
  constexpr int WJT = 4, WIT = 4;
  const int lane = threadIdx.x & 63;
  const int wid = threadIdx.x >> 6;
  const int wj = wid % 4, wi = wid / 4;
  const int jtbase = wj * WJT;
  const int ibase = blockIdx.x * 64 + wi * WIT * 16;
  const int lrow = lane & 15, lgrp = lane >> 4;

  int node[WIT];
  bool valid[WIT];
#pragma unroll
  for (int it = 0; it < WIT; it++) {
    int i = ibase + it * 16 + lrow;
    valid[it] = (i < n);
    node[it] = valid[it] ? i : (n - 1);
  }

  f32x4 acc[WJT][WIT];
#pragma unroll
  for (int jt = 0; jt < WJT; jt++)
#pragma unroll
    for (int it = 0; it < WIT; it++) acc[jt][it] = (f32x4){0.f, 0.f, 0.f, 0.f};

#pragma unroll
  for (int ks = 0; ks < 4; ks++) {
    float sck[8], shk[8];
    if (BN) {
      int cb = ks * 32 + lgrp * 8;
#pragma unroll
      for (int c = 0; c < 8; c++) { sck[c] = bnsc[cb + c]; shk[c] = bnsh[cb + c]; }
    }
    bf16x8 awh[WJT], awl[WJT];
#pragma unroll
    for (int jt = 0; jt < WJT; jt++) {
      int jg = jtbase + jt;
      const unsigned short* base = Wp + ((jg >= 8) ? 32768 : 0);
      size_t fo = (size_t)(((jg & 7) * 4 + ks) * 64 + lane) * 8;
      awh[jt] = *(const bf16x8*)(base + fo);
      awl[jt] = *(const bf16x8*)(base + fo + 16384);
    }
#pragma unroll
    for (int it = 0; it < WIT; it++) {
      const float* src = Af + (size_t)node[it] * 128 + ks * 32 + lgrp * 8;
      float4 u0 = *(const float4*)src;
      float4 u1 = *(const float4*)(src + 4);
      float vv[8] = {u0.x, u0.y, u0.z, u0.w, u1.x, u1.y, u1.z, u1.w};
      if (BN) {
#pragma unroll
        for (int c = 0; c < 8; c++) vv[c] = fmaxf(vv[c] * sck[c] + shk[c], 0.f);
      }
      bf16x8 bhh, bhl;
      split8(vv, bhh, bhl);
#pragma unroll
      for (int jt = 0; jt < WJT; jt++) {
        acc[jt][it] = __builtin_amdgcn_mfma_f32_16x16x32_bf16(awh[jt], bhh, acc[jt][it], 0, 0, 0);
        acc[jt][it] = __builtin_amdgcn_mfma_f32_16x16x32_bf16(awl[jt], bhh, acc[jt][it], 0, 0, 0);
        acc[jt][it] = __builtin_amdgcn_mfma_f32_16x16x32_bf16(awh[jt], bhl, acc[jt][it], 0, 0, 0);
      }
    }
  }

#pragma unroll
  for (int it = 0; it < WIT; it++) {
    if (!valid[it]) continue;
    float d0v = dinv[node[it]];
    float d1v = dinv[N + node[it]];
#pragma unroll
    for (int jt = 0; jt < WJT; jt++) {
      int jg = jtbase + jt;
      float s = (jg < 8) ? d0v : d1v;
      _Float16 o[4];
#pragma unroll
      for (int c = 0; c < 4; c++) o[c] = (_Float16)(acc[jt][it][c] * s);
      _Float16* base = (jg < 8)
          ? (tab0 + (size_t)node[it] * 128 + jg * 16)
          : (tab1 + (size_t)node[it] * 128 + (jg - 8) * 16);
      *(uint2*)(base + lgrp * 4) = *(uint2*)o;
    }
  }
}

// ---------------- gather + fused BN stats ----------------
__global__ __launch_bounds__(256) void gather_kernel(
    const _Float16* __restrict__ tab0, const _Float16* __restrict__ tab1,
    const float* __restrict__ dinv, const int* __restrict__ off,
    const int* __restrict__ csr,
    const float* __restrict__ b0, const float* __restrict__ b1,
    float* __restrict__ outh, float* __restrict__ stats, int n, int N) {
  __shared__ float reds[4][128];
  __shared__ float redq[4][128];
  int t = threadIdx.x;
  int g = t >> 4, l = t & 15;
  int node = blockIdx.x * 16 + g;
  bool valid = node < n;
  int nd = valid ? node : 0;
  const f16x8* t0 = (const f16x8*)tab0;
  const f16x8* t1 = (const f16x8*)tab1;
  float s0[8] = {0,0,0,0,0,0,0,0}, s1[8] = {0,0,0,0,0,0,0,0};
  if (valid) {
    f16x8 v = t0[(size_t)nd * 16 + l];
#pragma unroll
    for (int c = 0; c < 8; c++) s0[c] = (float)v[c];
    v = t1[(size_t)nd * 16 + l];
#pragma unroll
    for (int c = 0; c < 8; c++) s1[c] = (float)v[c];
  }
  int a = valid ? off[nd] : 0, b = valid ? off[nd + 1] : 0;
  int j = a;
  for (; j + 1 < b; j += 2) {
    int sa = csr[j], sb = csr[j + 1];
    f16x8 va = t0[(size_t)sa * 16 + l];
    f16x8 vb = t0[(size_t)sb * 16 + l];
#pragma unroll
    for (int c = 0; c < 8; c++) s0[c] += (float)va[c] + (float)vb[c];
  }
  if (j < b) {
    f16x8 va = t0[(size_t)csr[j] * 16 + l];
#pragma unroll
    for (int c = 0; c < 8; c++) s0[c] += (float)va[c];
  }
  a = valid ? off[N + nd] : 0; b = valid ? off[N + nd + 1] : 0;
  j = a;
  for (; j + 1 < b; j += 2) {
    int sa = csr[j], sb = csr[j + 1];
    f16x8 va = t1[(size_t)sa * 16 + l];
    f16x8 vb = t1[(size_t)sb * 16 + l];
#pragma unroll
    for (int c = 0; c < 8; c++) s1[c] += (float)va[c] + (float)vb[c];
  }
  if (j < b) {
    f16x8 va = t1[(size_t)csr[j] * 16 + l];
#pragma unroll
    for (int c = 0; c < 8; c++) s1[c] += (float)va[c];
  }
  float o[8] = {0,0,0,0,0,0,0,0};
  if (valid) {
    float d0 = dinv[nd], d1 = dinv[N + nd];
    const float4* B0 = (const float4*)(b0 + l * 8);
    const float4* B1 = (const float4*)(b1 + l * 8);
    float4 ba0 = B0[0], ba1 = B0[1], bb0 = B1[0], bb1 = B1[1];
    float bs[8] = {ba0.x + bb0.x, ba0.y + bb0.y, ba0.z + bb0.z, ba0.w + bb0.w,
                   ba1.x + bb1.x, ba1.y + bb1.y, ba1.z + bb1.z, ba1.w + bb1.w};
#pragma unroll
    for (int c = 0; c < 8; c++) o[c] = d0 * s0[c] + d1 * s1[c] + bs[c];
    float* dst = outh + (size_t)nd * 128 + l * 8;
    *(float4*)dst = make_float4(o[0], o[1], o[2], o[3]);
    *(float4*)(dst + 4) = make_float4(o[4], o[5], o[6], o[7]);
  }
  float sv[8], q[8];
#pragma unroll
  for (int c = 0; c < 8; c++) { sv[c] = o[c]; q[c] = o[c] * o[c]; }
#pragma unroll
  for (int c = 0; c < 8; c++) {
    sv[c] += __shfl_xor(sv[c], 16); sv[c] += __shfl_xor(sv[c], 32);
    q[c] += __shfl_xor(q[c], 16);  q[c] += __shfl_xor(q[c], 32);
  }
  int lane = t & 63, wid = t >> 6;
  if (lane < 16) {
#pragma unroll
    for (int c = 0; c < 8; c++) { reds[wid][lane * 8 + c] = sv[c]; redq[wid][lane * 8 + c] = q[c]; }
  }
  __syncthreads();
  if (t < 128) {
    float ts = reds[0][t] + reds[1][t] + reds[2][t] + reds[3][t];
    float tq = redq[0][t] + redq[1][t] + redq[2][t] + redq[3][t];
    int cp = blockIdx.x & 7;
    atomicAdd(&stats[cp * 128 + t], ts);
    atomicAdd(&stats[1024 + cp * 128 + t], tq);
  }
}

// ---------------- e-pair head: e1 (tanh) + e2 (tanh+l2norm), BN folded ----------------
// 4 waves: wj=wid%2 selects head, wi=wid/2 selects node subtile; 64 nodes/block.
__global__ __launch_bounds__(256) void mm_epair(
    const unsigned short* __restrict__ Wp,   // slot 6 (emb1), slot 7 (emb2)
    const float* __restrict__ h, const float* __restrict__ stats,
    const float* __restrict__ g2, const float* __restrict__ bt2,
    const float* __restrict__ emb1_b, const float* __restrict__ emb2_b,
    float* __restrict__ out, int n, float invn) {
  __shared__ float bnsc[128], bnsh[128];
  {
    int t = threadIdx.x;
    if (t < 128) {
      float s = 0.f, q = 0.f;
#pragma unroll
      for (int r = 0; r < 8; r++) { s += stats[r * 128 + t]; q += stats[1024 + r * 128 + t]; }
      float mu = s * invn, var = q * invn - mu * mu;
      float sc = g2[t] * rsqrtf(var + 1e-5f);
      bnsc[t] = sc; bnsh[t] = bt2[t] - mu * sc;
    }
    __syncthreads();
  }
  constexpr int WIT = 2;
  const int lane = threadIdx.x & 63;
  const int wid = threadIdx.x >> 6;
  const int wj = wid & 1, wi = wid >> 1;
  const int ibase = blockIdx.x * 64 + wi * WIT * 16;
  const int lrow = lane & 15, lgrp = lane >> 4;
  const unsigned short* slot = Wp + (size_t)(6 + wj) * 32768;
  const float* bias = wj ? emb2_b : emb1_b;
  const size_t ND = (size_t)n * 128;

  int node[WIT];
  bool valid[WIT];
#pragma unroll
  for (int it = 0; it < WIT; it++) {
    int i = ibase + it * 16 + lrow;
    valid[it] = (i < n);
    node[it] = valid[it] ? i : (n - 1);
  }

  f32x4 acc[8][WIT];
#pragma unroll
  for (int jt = 0; jt < 8; jt++) {
    float4 b4 = *(const float4*)(bias + jt * 16 + lgrp * 4);
#pragma unroll
    for (int it = 0; it < WIT; it++) acc[jt][it] = (f32x4){b4.x, b4.y, b4.z, b4.w};
  }

#pragma unroll
  for (int ks = 0; ks < 4; ks++) {
    int cb = ks * 32 + lgrp * 8;
    float sck[8], shk[8];
#pragma unroll
    for (int c = 0; c < 8; c++) { sck[c] = bnsc[cb + c]; shk[c] = bnsh[cb + c]; }
    bf16x8 awh[8], awl[8];
#pragma unroll
    for (int jt = 0; jt < 8; jt++) {
      size_t fo = (size_t)((jt * 4 + ks) * 64 + lane) * 8;
      awh[jt] = *(const bf16x8*)(slot + fo);
      awl[jt] = *(const bf16x8*)(slot + fo + 16384);
    }
#pragma unroll
    for (int it = 0; it < WIT; it++) {
      const float* src = h + (size_t)node[it] * 128 + ks * 32 + lgrp * 8;
      float4 u0 = *(const float4*)src;
      float4 u1 = *(const float4*)(src + 4);
      float vv[8] = {u0.x, u0.y, u0.z, u0.w, u1.x, u1.y, u1.z, u1.w};
#pragma unroll
      for (int c = 0; c < 8; c++) vv[c] = vv[c] * sck[c] + shk[c];
      bf16x8 bhh, bhl;
      split8(vv, bhh, bhl);
#pragma unroll
      for (int jt = 0; jt < 8; jt++) {
        acc[jt][it] = __builtin_amdgcn_mfma_f32_16x16x32_bf16(awh[jt], bhh, acc[jt][it], 0, 0, 0);
        acc[jt][it] = __builtin_amdgcn_mfma_f32_16x16x32_bf16(awl[jt], bhh, acc[jt][it], 0, 0, 0);
        acc[jt][it] = __builtin_amdgcn_mfma_f32_16x16x32_bf16(awh[jt], bhl, acc[jt][it], 0, 0, 0);
      }
    }
  }

#pragma unroll
  for (int jt = 0; jt < 8; jt++)
#pragma unroll
    for (int it = 0; it < WIT; it++)
#pragma unroll
      for (int c = 0; c < 4; c++) acc[jt][it][c] = tanhf(acc[jt][it][c]);

  if (wj) {  // l2norm for e2
#pragma unroll
    for (int it = 0; it < WIT; it++) {
      float rs = 0.f;
#pragma unroll
      for (int jt = 0; jt < 8; jt++)
#pragma unroll
        for (int c = 0; c < 4; c++) rs += acc[jt][it][c] * acc[jt][it][c];
      rs += __shfl_xor(rs, 16);
      rs += __shfl_xor(rs, 32);
      float scl = 1.f / fmaxf(sqrtf(rs), 1e-12f);
#pragma unroll
      for (int jt = 0; jt < 8; jt++)
#pragma unroll
        for (int c = 0; c < 4; c++) acc[jt][it][c] *= scl;
    }
  }
  float* ob = out + (size_t)wj * ND;
#pragma unroll
  for (int it = 0; it < WIT; it++) {
    if (!valid[it]) continue;
#pragma unroll
    for (int jt = 0; jt < 8; jt++)
      *(float4*)(ob + (size_t)node[it] * 128 + jt * 16 + lgrp * 4) =
          make_float4(acc[jt][it][0], acc[jt][it][1], acc[jt][it][2], acc[jt][it][3]);
  }
}

// ---------------- head matmul: EPI 1=relu, 4=l2norm ----------------
template <int EPI>
__global__ __launch_bounds__(256) void mm_head(
    const unsigned short* __restrict__ slot, const float* __restrict__ Af,
    const float* __restrict__ bias, float* __restrict__ outf, int n) {
  constexpr int WIT = 2;
  const int lane = threadIdx.x & 63;
  const int wid = threadIdx.x >> 6;
  const int ibase = blockIdx.x * 128 + wid * WIT * 16;
  const int lrow = lane & 15, lgrp = lane >> 4;

  int node[WIT];
  bool valid[WIT];
#pragma unroll
  for (int it = 0; it < WIT; it++) {
    int i = ibase + it * 16 + lrow;
    valid[it] = (i < n);
    node[it] = valid[it] ? i : (n - 1);
  }

  f32x4 acc[8][WIT];
#pragma unroll
  for (int jt = 0; jt < 8; jt++) {
    float4 b4 = *(const float4*)(bias + jt * 16 + lgrp * 4);
#pragma unroll
    for (int it = 0; it < WIT; it++) acc[jt][it] = (f32x4){b4.x, b4.y, b4.z, b4.w};
  }

#pragma unroll
  for (int ks = 0; ks < 4; ks++) {
    bf16x8 awh[8], awl[8];
#pragma unroll
    for (int jt = 0; jt < 8; jt++) {
      size_t fo = (size_t)((jt * 4 + ks) * 64 + lane) * 8;
      awh[jt] = *(const bf16x8*)(slot + fo);
      awl[jt] = *(const bf16x8*)(slot + fo + 16384);
    }
#pragma unroll
    for (int it = 0; it < WIT; it++) {
      const float* src = Af + (size_t)node[it] * 128 + ks * 32 + lgrp * 8;
      float4 u0 = *(const float4*)src;
      float4 u1 = *(const float4*)(src + 4);
      float vv[8] = {u0.x, u0.y, u0.z, u0.w, u1.x, u1.y, u1.z, u1.w};
      bf16x8 bhh, bhl;
      split8(vv, bhh, bhl);
#pragma unroll
      for (int jt = 0; jt < 8; jt++) {
        acc[jt][it] = __builtin_amdgcn_mfma_f32_16x16x32_bf16(awh[jt], bhh, acc[jt][it], 0, 0, 0);
        acc[jt][it] = __builtin_amdgcn_mfma_f32_16x16x32_bf16(awl[jt], bhh, acc[jt][it], 0, 0, 0);
        acc[jt][it] = __builtin_amdgcn_mfma_f32_16x16x32_bf16(awh[jt], bhl, acc[jt][it], 0, 0, 0);
      }
    }
  }

  if (EPI == 1) {
#pragma unroll
    for (int jt = 0; jt < 8; jt++)
#pragma unroll
      for (int it = 0; it < WIT; it++)
#pragma unroll
        for (int c = 0; c < 4; c++) acc[jt][it][c] = fmaxf(acc[jt][it][c], 0.f);
  }
  if (EPI == 4) {
#pragma unroll
    for (int it = 0; it < WIT; it++) {
      float rs = 0.f;
#pragma unroll
      for (int jt = 0; jt < 8; jt++)
#pragma unroll
        for (int c = 0; c < 4; c++) rs += acc[jt][it][c] * acc[jt][it][c];
      rs += __shfl_xor(rs, 16);
      rs += __shfl_xor(rs, 32);
      float scl = 1.f / fmaxf(sqrtf(rs), 1e-12f);
#pragma unroll
      for (int jt = 0; jt < 8; jt++)
#pragma unroll
        for (int c = 0; c < 4; c++) acc[jt][it][c] *= scl;
    }
  }
#pragma unroll
  for (int it = 0; it < WIT; it++) {
    if (!valid[it]) continue;
#pragma unroll
    for (int jt = 0; jt < 8; jt++)
      *(float4*)(outf + (size_t)node[it] * 128 + jt * 16 + lgrp * 4) =
          make_float4(acc[jt][it][0], acc[jt][it][1], acc[jt][it][2], acc[jt][it][3]);
  }
}

// ---------------- launch ----------------
extern "C" void kernel_launch(void* const* d_in, const int* in_sizes, int n_in,
                              void* d_out, int out_size, void* d_ws, size_t ws_size,
                              hipStream_t stream) {
  const float* x      = (const float*)d_in[0];
  const int*   ei0    = (const int*)d_in[1];
  const int*   ei1    = (const int*)d_in[2];
  const float* W0     = (const float*)d_in[3];
  const float* b0     = (const float*)d_in[4];
  const float* W1     = (const float*)d_in[5];
  const float* b1     = (const float*)d_in[6];
  const float* gamma  = (const float*)d_in[7];
  const float* beta   = (const float*)d_in[8];
  const float* emb1_W = (const float*)d_in[9];
  const float* emb1_b = (const float*)d_in[10];
  const float* emb2_W = (const float*)d_in[11];
  const float* emb2_b = (const float*)d_in[12];
  const float* ph1_Wa = (const float*)d_in[13];
  const float* ph1_ba = (const float*)d_in[14];
  const float* ph1_Wb = (const float*)d_in[15];
  const float* ph1_bb = (const float*)d_in[16];
  const float* ph2_Wa = (const float*)d_in[17];
  const float* ph2_ba = (const float*)d_in[18];
  const float* ph2_Wb = (const float*)d_in[19];
  const float* ph2_bb = (const float*)d_in[20];

  const int N = in_sizes[0] / D;
  const int E = in_sizes[1] / 2;
  const int N2 = 2 * N;
  const size_t ND = (size_t)N * D;
  const float invn = 1.0f / (float)N;
  float* out = (float*)d_out;

  char* p = (char*)d_ws;
  char* pend = p + ws_size;
  auto carve = [&](size_t bytes) -> void* {
    void* r = (void*)p;
    p += (bytes + 255) & ~(size_t)255;
    return r;
  };
  int*   cnt   = (int*)carve((size_t)N2 * 4);
  int*   off   = (int*)carve((size_t)(N2 + 1) * 4);
  float* dinv  = (float*)carve((size_t)N2 * 4);
  int*   csr   = (int*)carve((size_t)2 * E * 4);
  int*   bsum  = (int*)carve(256 * 4);
  float* stats = (float*)carve(2048 * 4);
  unsigned short* Wp = (unsigned short*)carve((size_t)12 * 32768 * 2);
  float* tbuf  = (float*)carve(ND * 4);   // relu intermediates

  float* hbuf;
  _Float16 *tab0, *tab1;
  size_t avail = (size_t)(pend - p);
  if (avail >= 8 * ND + 1024) {
    hbuf = (float*)carve(4 * ND);
    tab0 = (_Float16*)carve(2 * ND);
    tab1 = (_Float16*)carve(2 * ND);
  } else if (avail >= 4 * ND + 512) {
    hbuf = out + 2 * ND;
    tab0 = (_Float16*)carve(2 * ND);
    tab1 = (_Float16*)carve(2 * ND);
  } else {
    hbuf = out + 2 * ND;
    tab0 = (_Float16*)(out + 3 * ND);
    tab1 = tab0 + ND;
  }

  const int TPB = 256;
  const int gridE = (E + TPB - 1) / TPB;
  const int nbScan = (N2 + 511) / 512;
  const int gridDual = (N + 63) / 64;
  const int gridGath = (N + 15) / 16;
  const int gridE2 = (N + 63) / 64;
  const int gridHd = (N + 127) / 128;

  WPtrs P;
  P.w[0] = W0;                     P.w[1] = W1;
  P.w[2] = W0 + (size_t)D * D;     P.w[3] = W1 + (size_t)D * D;
  P.w[4] = W0 + (size_t)2 * D * D; P.w[5] = W1 + (size_t)2 * D * D;
  P.w[6] = emb1_W; P.w[7] = emb2_W;
  P.w[8] = ph1_Wa; P.w[9] = ph1_Wb;
  P.w[10] = ph2_Wa; P.w[11] = ph2_Wb;
  pack_all_kernel<<<768, TPB, 0, stream>>>(P, Wp);

  hipMemsetAsync(cnt, 0, (size_t)N2 * 4, stream);
  count_kernel<<<gridE, TPB, 0, stream>>>(ei0 + E, ei1 + E, cnt, E, N);
  scan_part_kernel<<<nbScan, TPB, 0, stream>>>(cnt, off, bsum, N2);
  scan_bsum_kernel<<<1, TPB, 0, stream>>>(bsum, nbScan, off + N2);
  scan_add_kernel<<<nbScan, TPB, 0, stream>>>(off, bsum, cnt, dinv, N2);
  fill_kernel<<<gridE, TPB, 0, stream>>>(ei0, ei1, off, cnt, csr, E, N);

  for (int i = 0; i < 3; i++) {
    const unsigned short* wslot = Wp + (size_t)(2 * i) * 32768;
    if (i == 0) {
      mm_dual<0><<<gridDual, TPB, 0, stream>>>(wslot, x, nullptr, nullptr, nullptr,
                                               dinv, tab0, tab1, N, N, invn);
    } else {
      mm_dual<1><<<gridDual, TPB, 0, stream>>>(wslot, hbuf, stats, gamma + (i - 1) * D,
                                               beta + (i - 1) * D, dinv, tab0, tab1, N, N, invn);
    }
    hipMemsetAsync(stats, 0, 2048 * 4, stream);
    gather_kernel<<<gridGath, TPB, 0, stream>>>(tab0, tab1, dinv, off, csr,
                                                b0 + i * D, b1 + i * D, hbuf, stats, N, N);
  }

  // heads: e1+e2 fused (share h read, BN folded), then t/p chains
  mm_epair<<<gridE2, TPB, 0, stream>>>(Wp, hbuf, stats, gamma + 2 * D, beta + 2 * D,
                                       emb1_b, emb2_b, out, N, invn);
  mm_head<1><<<gridHd, TPB, 0, stream>>>(Wp + (size_t)8 * 32768, out, ph1_ba, tbuf, N);
  mm_head<4><<<gridHd, TPB, 0, stream>>>(Wp + (size_t)9 * 32768, tbuf, ph1_bb, out + 2 * ND, N);
  mm_head<1><<<gridHd, TPB, 0, stream>>>(Wp + (size_t)10 * 32768, out + ND, ph2_ba, tbuf, N);
  mm_head<4><<<gridHd, TPB, 0, stream>>>(Wp + (size_t)11 * 32768, tbuf, ph2_bb, out + 3 * ND, N);
}

// Round 7
// 418.053 us; speedup vs baseline: 1.0004x; 1.0004x over previous
//
#include <hip/hip_runtime.h>
#include <cstdint>
#include <cstddef>

#define D 128

typedef __attribute__((ext_vector_type(8))) short bf16x8;
typedef __attribute__((ext_vector_type(4))) float f32x4;
typedef __attribute__((ext_vector_type(8))) _Float16 f16x8;

__device__ __forceinline__ unsigned short f2bf(float f) {
  unsigned int u = __float_as_uint(f);
  unsigned int r = u + 0x7FFFu + ((u >> 16) & 1u);
  return (unsigned short)(r >> 16);
}
__device__ __forceinline__ float bf2f(unsigned short h) {
  return __uint_as_float((unsigned int)h << 16);
}
__device__ __forceinline__ float fast_tanh(float x) {
  float cx = fminf(fmaxf(x, -15.f), 15.f);
  float e = __expf(2.f * cx);
  return (e - 1.f) * __builtin_amdgcn_rcpf(e + 1.f);
}

// ---------------- weight packing (all 12 matrices, one launch) ----------------
// slot m: hi at Wp[m*32768 + r], lo at Wp[m*32768 + 16384 + r]
// r = ((jt*4+ks)*64+lane)*8 + b  ->  W[(ks*32+(lane>>4)*8+b)*128 + jt*16+(lane&15)]
struct WPtrs { const float* w[12]; };

__global__ __launch_bounds__(256) void pack_all_kernel(WPtrs P, unsigned short* __restrict__ Wp) {
  int tid = blockIdx.x * blockDim.x + threadIdx.x;  // 0..196607
  int m = tid >> 14;
  int r = tid & 16383;
  int b = r & 7, lane = (r >> 3) & 63, ks = (r >> 9) & 3, jt = r >> 11;
  int k = ks * 32 + ((lane >> 4) << 3) + b;
  int j = jt * 16 + (lane & 15);
  float w = P.w[m][k * 128 + j];
  unsigned short h = f2bf(w);
  Wp[m * 32768 + r] = h;
  Wp[m * 32768 + 16384 + r] = f2bf(w - bf2f(h));
}

// ---------------- CSR build (concatenated: type0=[0,N), type1=[N,2N)) ----------------
__global__ void count_kernel(const int* __restrict__ d0, const int* __restrict__ d1,
                             int* __restrict__ cnt, int E, int N) {
  int e = blockIdx.x * blockDim.x + threadIdx.x;
  if (e < E) {
    atomicAdd(&cnt[d0[e]], 1);
    atomicAdd(&cnt[N + d1[e]], 1);
  }
}

__global__ __launch_bounds__(256) void scan_part_kernel(const int* __restrict__ cnt,
                                                        int* __restrict__ off,
                                                        int* __restrict__ bsum, int n2) {
  __shared__ int sh[256];
  int t = threadIdx.x;
  int i0 = blockIdx.x * 512 + 2 * t;
  int a0 = (i0 < n2) ? cnt[i0] : 0;
  int a1 = (i0 + 1 < n2) ? cnt[i0 + 1] : 0;
  int s = a0 + a1;
  sh[t] = s;
  __syncthreads();
  for (int d = 1; d < 256; d <<= 1) {
    int v = (t >= d) ? sh[t - d] : 0;
    __syncthreads();
    sh[t] += v;
    __syncthreads();
  }
  int p = sh[t] - s;
  if (i0 < n2) off[i0] = p;
  if (i0 + 1 < n2) off[i0 + 1] = p + a0;
  if (t == 255) bsum[blockIdx.x] = sh[255];
}

__global__ __launch_bounds__(256) void scan_bsum_kernel(int* __restrict__ bsum, int nb,
                                                        int* __restrict__ off_total) {
  __shared__ int sh[256];
  int t = threadIdx.x;
  int s = (t < nb) ? bsum[t] : 0;
  sh[t] = s;
  __syncthreads();
  for (int d = 1; d < 256; d <<= 1) {
    int v = (t >= d) ? sh[t - d] : 0;
    __syncthreads();
    sh[t] += v;
    __syncthreads();
  }
  if (t < nb) bsum[t] = sh[t] - s;
  if (t == 255) *off_total = sh[255];
}

__global__ __launch_bounds__(256) void scan_add_kernel(int* __restrict__ off,
                                                       const int* __restrict__ bsum,
                                                       int* __restrict__ cnt,
                                                       float* __restrict__ dinv, int n2) {
  int add = bsum[blockIdx.x];
  int base = blockIdx.x * 512;
#pragma unroll
  for (int u = 0; u < 2; u++) {
    int i = base + threadIdx.x + u * 256;
    if (i < n2) {
      off[i] += add;
      dinv[i] = rsqrtf((float)cnt[i] + 1.0f);
      cnt[i] = 0;
    }
  }
}

__global__ void fill_kernel(const int* __restrict__ ei0, const int* __restrict__ ei1,
                            const int* __restrict__ off, int* __restrict__ cnt,
                            int* __restrict__ csr, int E, int N) {
  int e = blockIdx.x * blockDim.x + threadIdx.x;
  if (e < E) {
    int s = ei0[e], d = ei0[E + e];
    int p = atomicAdd(&cnt[d], 1);
    csr[off[d] + p] = s;
    s = ei1[e]; d = ei1[E + e];
    p = atomicAdd(&cnt[N + d], 1);
    csr[off[N + d] + p] = s;
  }
}

// ---------------- split helpers ----------------
__device__ __forceinline__ void split8(const float vv[8], bf16x8& hh, bf16x8& hl) {
#pragma unroll
  for (int c = 0; c < 8; c++) {
    unsigned short h = f2bf(vv[c]);
    hh[c] = (short)h;
    hl[c] = (short)f2bf(vv[c] - bf2f(h));
  }
}

// ---------------- dual GCN matmul (operand-swapped, split precision) ----------------
template <int BN>
__global__ __launch_bounds__(256) void mm_dual(
    const unsigned short* __restrict__ Wp, const float* __restrict__ Af,
    const float* __restrict__ stats, const float* __restrict__ g0,
    const float* __restrict__ bt0, const float* __restrict__ dinv,
    _Float16* __restrict__ tab0, _Float16* __restrict__ tab1,
    int n, int N, float invn) {
  __shared__ float bnsc[128], bnsh[128];
  if (BN) {
    int t = threadIdx.x;
    if (t < 128) {
      float s = 0.f, q = 0.f;
#pragma unroll
      for (int r = 0; r < 8; r++) { s += stats[r * 128 + t]; q += stats[1024 + r * 128 + t]; }
      float mu = s * invn, var = q * invn - mu * mu;
      float sc = g0[t] * rsqrtf(var + 1e-5f);
      bnsc[t] = sc; bnsh[t] = bt0[t] - mu * sc;
    }
    __syncthreads();
  }
  constexpr int WJT = 4, WIT = 4;
  const int lane = threadIdx.x & 63;
  const int wid = threadIdx.x >> 6;
  const int wj = wid % 4, wi = wid / 4;
  const int jtbase = wj * WJT;
  const int ibase = blockIdx.x * 64 + wi * WIT * 16;
  const int lrow = lane & 15, lgrp = lane >> 4;

  int node[WIT];
  bool valid[WIT];
#pragma unroll
  for (int it = 0; it < WIT; it++) {
    int i = ibase + it * 16 + lrow;
    valid[it] = (i < n);
    node[it] = valid[it] ? i : (n - 1);
  }

  f32x4 acc[WJT][WIT];
#pragma unroll
  for (int jt = 0; jt < WJT; jt++)
#pragma unroll
    for (int it = 0; it < WIT; it++) acc[jt][it] = (f32x4){0.f, 0.f, 0.f, 0.f};

#pragma unroll
  for (int ks = 0; ks < 4; ks++) {
    float sck[8], shk[8];
    if (BN) {
      int cb = ks * 32 + lgrp * 8;
#pragma unroll
      for (int c = 0; c < 8; c++) { sck[c] = bnsc[cb + c]; shk[c] = bnsh[cb + c]; }
    }
    bf16x8 awh[WJT], awl[WJT];
#pragma unroll
    for (int jt = 0; jt < WJT; jt++) {
      int jg = jtbase + jt;
      const unsigned short* base = Wp + ((jg >= 8) ? 32768 : 0);
      size_t fo = (size_t)(((jg & 7) * 4 + ks) * 64 + lane) * 8;
      awh[jt] = *(const bf16x8*)(base + fo);
      awl[jt] = *(const bf16x8*)(base + fo + 16384);
    }
#pragma unroll
    for (int it = 0; it < WIT; it++) {
      const float* src = Af + (size_t)node[it] * 128 + ks * 32 + lgrp * 8;
      float4 u0 = *(const float4*)src;
      float4 u1 = *(const float4*)(src + 4);
      float vv[8] = {u0.x, u0.y, u0.z, u0.w, u1.x, u1.y, u1.z, u1.w};
      if (BN) {
#pragma unroll
        for (int c = 0; c < 8; c++) vv[c] = fmaxf(vv[c] * sck[c] + shk[c], 0.f);
      }
      bf16x8 bhh, bhl;
      split8(vv, bhh, bhl);
#pragma unroll
      for (int jt = 0; jt < WJT; jt++) {
        acc[jt][it] = __builtin_amdgcn_mfma_f32_16x16x32_bf16(awh[jt], bhh, acc[jt][it], 0, 0, 0);
        acc[jt][it] = __builtin_amdgcn_mfma_f32_16x16x32_bf16(awl[jt], bhh, acc[jt][it], 0, 0, 0);
        acc[jt][it] = __builtin_amdgcn_mfma_f32_16x16x32_bf16(awh[jt], bhl, acc[jt][it], 0, 0, 0);
      }
    }
  }

#pragma unroll
  for (int it = 0; it < WIT; it++) {
    if (!valid[it]) continue;
    float d0v = dinv[node[it]];
    float d1v = dinv[N + node[it]];
#pragma unroll
    for (int jt = 0; jt < WJT; jt++) {
      int jg = jtbase + jt;
      float s = (jg < 8) ? d0v : d1v;
      _Float16 o[4];
#pragma unroll
      for (int c = 0; c < 4; c++) o[c] = (_Float16)(acc[jt][it][c] * s);
      _Float16* base = (jg < 8)
          ? (tab0 + (size_t)node[it] * 128 + jg * 16)
          : (tab1 + (size_t)node[it] * 128 + (jg - 8) * 16);
      *(uint2*)(base + lgrp * 4) = *(uint2*)o;
    }
  }
}

// ---------------- gather + fused BN stats ----------------
__global__ __launch_bounds__(256) void gather_kernel(
    const _Float16* __restrict__ tab0, const _Float16* __restrict__ tab1,
    const float* __restrict__ dinv, const int* __restrict__ off,
    const int* __restrict__ csr,
    const float* __restrict__ b0, const float* __restrict__ b1,
    float* __restrict__ outh, float* __restrict__ stats, int n, int N) {
  __shared__ float reds[4][128];
  __shared__ float redq[4][128];
  int t = threadIdx.x;
  int g = t >> 4, l = t & 15;
  int node = blockIdx.x * 16 + g;
  bool valid = node < n;
  int nd = valid ? node : 0;
  const f16x8* t0 = (const f16x8*)tab0;
  const f16x8* t1 = (const f16x8*)tab1;
  float s0[8] = {0,0,0,0,0,0,0,0}, s1[8] = {0,0,0,0,0,0,0,0};
  if (valid) {
    f16x8 v = t0[(size_t)nd * 16 + l];
#pragma unroll
    for (int c = 0; c < 8; c++) s0[c] = (float)v[c];
    v = t1[(size_t)nd * 16 + l];
#pragma unroll
    for (int c = 0; c < 8; c++) s1[c] = (float)v[c];
  }
  int a = valid ? off[nd] : 0, b = valid ? off[nd + 1] : 0;
  int j = a;
  for (; j + 3 < b; j += 4) {
    int i0 = csr[j], i1 = csr[j + 1], i2 = csr[j + 2], i3 = csr[j + 3];
    f16x8 v0 = t0[(size_t)i0 * 16 + l];
    f16x8 v1 = t0[(size_t)i1 * 16 + l];
    f16x8 v2 = t0[(size_t)i2 * 16 + l];
    f16x8 v3 = t0[(size_t)i3 * 16 + l];
#pragma unroll
    for (int c = 0; c < 8; c++)
      s0[c] += ((float)v0[c] + (float)v1[c]) + ((float)v2[c] + (float)v3[c]);
  }
  for (; j < b; j++) {
    f16x8 va = t0[(size_t)csr[j] * 16 + l];
#pragma unroll
    for (int c = 0; c < 8; c++) s0[c] += (float)va[c];
  }
  a = valid ? off[N + nd] : 0; b = valid ? off[N + nd + 1] : 0;
  j = a;
  for (; j + 3 < b; j += 4) {
    int i0 = csr[j], i1 = csr[j + 1], i2 = csr[j + 2], i3 = csr[j + 3];
    f16x8 v0 = t1[(size_t)i0 * 16 + l];
    f16x8 v1 = t1[(size_t)i1 * 16 + l];
    f16x8 v2 = t1[(size_t)i2 * 16 + l];
    f16x8 v3 = t1[(size_t)i3 * 16 + l];
#pragma unroll
    for (int c = 0; c < 8; c++)
      s1[c] += ((float)v0[c] + (float)v1[c]) + ((float)v2[c] + (float)v3[c]);
  }
  for (; j < b; j++) {
    f16x8 va = t1[(size_t)csr[j] * 16 + l];
#pragma unroll
    for (int c = 0; c < 8; c++) s1[c] += (float)va[c];
  }
  float o[8] = {0,0,0,0,0,0,0,0};
  if (valid) {
    float d0 = dinv[nd], d1 = dinv[N + nd];
    const float4* B0 = (const float4*)(b0 + l * 8);
    const float4* B1 = (const float4*)(b1 + l * 8);
    float4 ba0 = B0[0], ba1 = B0[1], bb0 = B1[0], bb1 = B1[1];
    float bs[8] = {ba0.x + bb0.x, ba0.y + bb0.y, ba0.z + bb0.z, ba0.w + bb0.w,
                   ba1.x + bb1.x, ba1.y + bb1.y, ba1.z + bb1.z, ba1.w + bb1.w};
#pragma unroll
    for (int c = 0; c < 8; c++) o[c] = d0 * s0[c] + d1 * s1[c] + bs[c];
    float* dst = outh + (size_t)nd * 128 + l * 8;
    *(float4*)dst = make_float4(o[0], o[1], o[2], o[3]);
    *(float4*)(dst + 4) = make_float4(o[4], o[5], o[6], o[7]);
  }
  float sv[8], q[8];
#pragma unroll
  for (int c = 0; c < 8; c++) { sv[c] = o[c]; q[c] = o[c] * o[c]; }
#pragma unroll
  for (int c = 0; c < 8; c++) {
    sv[c] += __shfl_xor(sv[c], 16); sv[c] += __shfl_xor(sv[c], 32);
    q[c] += __shfl_xor(q[c], 16);  q[c] += __shfl_xor(q[c], 32);
  }
  int lane = t & 63, wid = t >> 6;
  if (lane < 16) {
#pragma unroll
    for (int c = 0; c < 8; c++) { reds[wid][lane * 8 + c] = sv[c]; redq[wid][lane * 8 + c] = q[c]; }
  }
  __syncthreads();
  if (t < 128) {
    float ts = reds[0][t] + reds[1][t] + reds[2][t] + reds[3][t];
    float tq = redq[0][t] + redq[1][t] + redq[2][t] + redq[3][t];
    int cp = blockIdx.x & 7;
    atomicAdd(&stats[cp * 128 + t], ts);
    atomicAdd(&stats[1024 + cp * 128 + t], tq);
  }
}

// ---------------- paired head matmuls: JSPLIT=2, WJT=4, WIT=4, 128 nodes/block ----
// MODE 0: e-pair  (BN folded on A; m=0 -> tanh, m=1 -> tanh+l2norm)
// MODE 1: t-pair  (relu)
// MODE 2: p-pair  (l2norm)
template <int MODE>
__global__ __launch_bounds__(256) void mm_heads(
    const unsigned short* __restrict__ Wp, int sl0, int sl1,
    const float* __restrict__ A0, const float* __restrict__ A1,
    const float* __restrict__ bias0, const float* __restrict__ bias1,
    float* __restrict__ out0, float* __restrict__ out1,
    const float* __restrict__ stats, const float* __restrict__ g2,
    const float* __restrict__ bt2, int G, int n, float invn) {
  __shared__ float bnsc[128], bnsh[128];
  __shared__ float l2red[2][4][16][2];
  if (MODE == 0) {
    int t = threadIdx.x;
    if (t < 128) {
      float s = 0.f, q = 0.f;
#pragma unroll
      for (int r = 0; r < 8; r++) { s += stats[r * 128 + t]; q += stats[1024 + r * 128 + t]; }
      float mu = s * invn, var = q * invn - mu * mu;
      float sc = g2[t] * rsqrtf(var + 1e-5f);
      bnsc[t] = sc; bnsh[t] = bt2[t] - mu * sc;
    }
    __syncthreads();
  }
  const int m = (blockIdx.x >= G) ? 1 : 0;
  const int base = (blockIdx.x - m * G) * 128;
  const unsigned short* slot = Wp + (size_t)(m ? sl1 : sl0) * 32768;
  const float* A = m ? A1 : A0;
  const float* bias = m ? bias1 : bias0;
  float* outp = m ? out1 : out0;
  const bool do_l2 = (MODE == 2) || (MODE == 0 && m == 1);

  const int lane = threadIdx.x & 63;
  const int wid = threadIdx.x >> 6;
  const int wj = wid & 1, wi = wid >> 1;
  const int lrow = lane & 15, lgrp = lane >> 4;
  const int jtbase = wj * 4;

  int node[4];
  bool valid[4];
#pragma unroll
  for (int it = 0; it < 4; it++) {
    int i = base + wi * 64 + it * 16 + lrow;
    valid[it] = (i < n);
    node[it] = valid[it] ? i : (n - 1);
  }

  f32x4 acc[4][4];
#pragma unroll
  for (int jt = 0; jt < 4; jt++) {
    float4 b4 = *(const float4*)(bias + (jtbase + jt) * 16 + lgrp * 4);
#pragma unroll
    for (int it = 0; it < 4; it++) acc[jt][it] = (f32x4){b4.x, b4.y, b4.z, b4.w};
  }

#pragma unroll
  for (int ks = 0; ks < 4; ks++) {
    float sck[8], shk[8];
    if (MODE == 0) {
      int cb = ks * 32 + lgrp * 8;
#pragma unroll
      for (int c = 0; c < 8; c++) { sck[c] = bnsc[cb + c]; shk[c] = bnsh[cb + c]; }
    }
    bf16x8 awh[4], awl[4];
#pragma unroll
    for (int jt = 0; jt < 4; jt++) {
      size_t fo = (size_t)(((jtbase + jt) * 4 + ks) * 64 + lane) * 8;
      awh[jt] = *(const bf16x8*)(slot + fo);
      awl[jt] = *(const bf16x8*)(slot + fo + 16384);
    }
#pragma unroll
    for (int it = 0; it < 4; it++) {
      const float* src = A + (size_t)node[it] * 128 + ks * 32 + lgrp * 8;
      float4 u0 = *(const float4*)src;
      float4 u1 = *(const float4*)(src + 4);
      float vv[8] = {u0.x, u0.y, u0.z, u0.w, u1.x, u1.y, u1.z, u1.w};
      if (MODE == 0) {
#pragma unroll
        for (int c = 0; c < 8; c++) vv[c] = vv[c] * sck[c] + shk[c];
      }
      bf16x8 bhh, bhl;
      split8(vv, bhh, bhl);
#pragma unroll
      for (int jt = 0; jt < 4; jt++) {
        acc[jt][it] = __builtin_amdgcn_mfma_f32_16x16x32_bf16(awh[jt], bhh, acc[jt][it], 0, 0, 0);
        acc[jt][it] = __builtin_amdgcn_mfma_f32_16x16x32_bf16(awl[jt], bhh, acc[jt][it], 0, 0, 0);
        acc[jt][it] = __builtin_amdgcn_mfma_f32_16x16x32_bf16(awh[jt], bhl, acc[jt][it], 0, 0, 0);
      }
    }
  }

  if (MODE == 0) {
#pragma unroll
    for (int jt = 0; jt < 4; jt++)
#pragma unroll
      for (int it = 0; it < 4; it++)
#pragma unroll
        for (int c = 0; c < 4; c++) acc[jt][it][c] = fast_tanh(acc[jt][it][c]);
  }
  if (MODE == 1) {
#pragma unroll
    for (int jt = 0; jt < 4; jt++)
#pragma unroll
      for (int it = 0; it < 4; it++)
#pragma unroll
        for (int c = 0; c < 4; c++) acc[jt][it][c] = fmaxf(acc[jt][it][c], 0.f);
  }

  float rsv[4];
  if (do_l2) {
#pragma unroll
    for (int it = 0; it < 4; it++) {
      float rs = 0.f;
#pragma unroll
      for (int jt = 0; jt < 4; jt++)
#pragma unroll
        for (int c = 0; c < 4; c++) rs += acc[jt][it][c] * acc[jt][it][c];
      rs += __shfl_xor(rs, 16);
      rs += __shfl_xor(rs, 32);
      rsv[it] = rs;
      if (lane < 16) l2red[wi][it][lane][wj] = rs;
    }
  }
  if (MODE != 1) __syncthreads();
  if (do_l2) {
#pragma unroll
    for (int it = 0; it < 4; it++) {
      float full = rsv[it] + l2red[wi][it][lrow][wj ^ 1];
      float scl = 1.f / fmaxf(sqrtf(full), 1e-12f);
#pragma unroll
      for (int jt = 0; jt < 4; jt++)
#pragma unroll
        for (int c = 0; c < 4; c++) acc[jt][it][c] *= scl;
    }
  }

#pragma unroll
  for (int it = 0; it < 4; it++) {
    if (!valid[it]) continue;
#pragma unroll
    for (int jt = 0; jt < 4; jt++)
      *(float4*)(outp + (size_t)node[it] * 128 + (jtbase + jt) * 16 + lgrp * 4) =
          make_float4(acc[jt][it][0], acc[jt][it][1], acc[jt][it][2], acc[jt][it][3]);
  }
}

// ---------------- launch ----------------
extern "C" void kernel_launch(void* const* d_in, const int* in_sizes, int n_in,
                              void* d_out, int out_size, void* d_ws, size_t ws_size,
                              hipStream_t stream) {
  const float* x      = (const float*)d_in[0];
  const int*   ei0    = (const int*)d_in[1];
  const int*   ei1    = (const int*)d_in[2];
  const float* W0     = (const float*)d_in[3];
  const float* b0     = (const float*)d_in[4];
  const float* W1     = (const float*)d_in[5];
  const float* b1     = (const float*)d_in[6];
  const float* gamma  = (const float*)d_in[7];
  const float* beta   = (const float*)d_in[8];
  const float* emb1_W = (const float*)d_in[9];
  const float* emb1_b = (const float*)d_in[10];
  const float* emb2_W = (const float*)d_in[11];
  const float* emb2_b = (const float*)d_in[12];
  const float* ph1_Wa = (const float*)d_in[13];
  const float* ph1_ba = (const float*)d_in[14];
  const float* ph1_Wb = (const float*)d_in[15];
  const float* ph1_bb = (const float*)d_in[16];
  const float* ph2_Wa = (const float*)d_in[17];
  const float* ph2_ba = (const float*)d_in[18];
  const float* ph2_Wb = (const float*)d_in[19];
  const float* ph2_bb = (const float*)d_in[20];

  const int N = in_sizes[0] / D;
  const int E = in_sizes[1] / 2;
  const int N2 = 2 * N;
  const size_t ND = (size_t)N * D;
  const float invn = 1.0f / (float)N;
  float* out = (float*)d_out;

  char* p = (char*)d_ws;
  char* pend = p + ws_size;
  auto carve = [&](size_t bytes) -> void* {
    void* r = (void*)p;
    p += (bytes + 255) & ~(size_t)255;
    return r;
  };
  int*   cnt   = (int*)carve((size_t)N2 * 4);
  int*   off   = (int*)carve((size_t)(N2 + 1) * 4);
  float* dinv  = (float*)carve((size_t)N2 * 4);
  int*   csr   = (int*)carve((size_t)2 * E * 4);
  int*   bsum  = (int*)carve(256 * 4);
  float* stats = (float*)carve(2048 * 4);
  unsigned short* Wp = (unsigned short*)carve((size_t)12 * 32768 * 2);
  float* tbuf  = (float*)carve(2 * ND * 4);   // t1, t2

  float* hbuf;
  _Float16 *tab0, *tab1;
  size_t avail = (size_t)(pend - p);
  if (avail >= 8 * ND + 1024) {
    hbuf = (float*)carve(4 * ND);
    tab0 = (_Float16*)carve(2 * ND);
    tab1 = (_Float16*)carve(2 * ND);
  } else if (avail >= 4 * ND + 512) {
    hbuf = out + 2 * ND;
    tab0 = (_Float16*)carve(2 * ND);
    tab1 = (_Float16*)carve(2 * ND);
  } else {
    hbuf = out + 2 * ND;
    tab0 = (_Float16*)(out + 3 * ND);
    tab1 = tab0 + ND;
  }

  const int TPB = 256;
  const int gridE = (E + TPB - 1) / TPB;
  const int nbScan = (N2 + 511) / 512;
  const int gridDual = (N + 63) / 64;
  const int gridGath = (N + 15) / 16;
  const int Ghd = (N + 127) / 128;

  WPtrs P;
  P.w[0] = W0;                     P.w[1] = W1;
  P.w[2] = W0 + (size_t)D * D;     P.w[3] = W1 + (size_t)D * D;
  P.w[4] = W0 + (size_t)2 * D * D; P.w[5] = W1 + (size_t)2 * D * D;
  P.w[6] = emb1_W; P.w[7] = emb2_W;
  P.w[8] = ph1_Wa; P.w[9] = ph1_Wb;
  P.w[10] = ph2_Wa; P.w[11] = ph2_Wb;
  pack_all_kernel<<<768, TPB, 0, stream>>>(P, Wp);

  hipMemsetAsync(cnt, 0, (size_t)N2 * 4, stream);
  count_kernel<<<gridE, TPB, 0, stream>>>(ei0 + E, ei1 + E, cnt, E, N);
  scan_part_kernel<<<nbScan, TPB, 0, stream>>>(cnt, off, bsum, N2);
  scan_bsum_kernel<<<1, TPB, 0, stream>>>(bsum, nbScan, off + N2);
  scan_add_kernel<<<nbScan, TPB, 0, stream>>>(off, bsum, cnt, dinv, N2);
  fill_kernel<<<gridE, TPB, 0, stream>>>(ei0, ei1, off, cnt, csr, E, N);

  for (int i = 0; i < 3; i++) {
    const unsigned short* wslot = Wp + (size_t)(2 * i) * 32768;
    if (i == 0) {
      mm_dual<0><<<gridDual, TPB, 0, stream>>>(wslot, x, nullptr, nullptr, nullptr,
                                               dinv, tab0, tab1, N, N, invn);
    } else {
      mm_dual<1><<<gridDual, TPB, 0, stream>>>(wslot, hbuf, stats, gamma + (i - 1) * D,
                                               beta + (i - 1) * D, dinv, tab0, tab1, N, N, invn);
    }
    hipMemsetAsync(stats, 0, 2048 * 4, stream);
    gather_kernel<<<gridGath, TPB, 0, stream>>>(tab0, tab1, dinv, off, csr,
                                                b0 + i * D, b1 + i * D, hbuf, stats, N, N);
  }

  // heads: 3 paired dispatches (e1+e2, t1+t2, p1+p2)
  mm_heads<0><<<2 * Ghd, TPB, 0, stream>>>(
      Wp, 6, 7, hbuf, hbuf, emb1_b, emb2_b, out, out + ND,
      stats, gamma + 2 * D, beta + 2 * D, Ghd, N, invn);
  mm_heads<1><<<2 * Ghd, TPB, 0, stream>>>(
      Wp, 8, 10, out, out + ND, ph1_ba, ph2_ba, tbuf, tbuf + ND,
      nullptr, nullptr, nullptr, Ghd, N, invn);
  mm_heads<2><<<2 * Ghd, TPB, 0, stream>>>(
      Wp, 9, 11, tbuf, tbuf + ND, ph1_bb, ph2_bb, out + 2 * ND, out + 3 * ND,
      nullptr, nullptr, nullptr, Ghd, N, invn);
}

// Round 8
// 348.441 us; speedup vs baseline: 1.2003x; 1.1998x over previous
//
#include <hip/hip_runtime.h>
#include <cstdint>
#include <cstddef>

#define D 128

typedef __attribute__((ext_vector_type(8))) short bf16x8;
typedef __attribute__((ext_vector_type(4))) float f32x4;
typedef __attribute__((ext_vector_type(8))) _Float16 f16x8;

__device__ __forceinline__ unsigned short f2bf(float f) {
  unsigned int u = __float_as_uint(f);
  unsigned int r = u + 0x7FFFu + ((u >> 16) & 1u);
  return (unsigned short)(r >> 16);
}
__device__ __forceinline__ float bf2f(unsigned short h) {
  return __uint_as_float((unsigned int)h << 16);
}
__device__ __forceinline__ float fast_tanh(float x) {
  float cx = fminf(fmaxf(x, -15.f), 15.f);
  float e = __expf(2.f * cx);
  return (e - 1.f) * __builtin_amdgcn_rcpf(e + 1.f);
}

// ---------------- fused pack (12 weight mats) + degree count ----------------
// pack: slot m hi at Wp[m*32768+r], lo at +16384;
// r=((jt*4+ks)*64+lane)*8+b -> W[(ks*32+(lane>>4)*8+b)*128 + jt*16+(lane&15)]
struct WPtrs { const float* w[12]; };

__global__ __launch_bounds__(256) void packcount_kernel(
    WPtrs P, unsigned short* __restrict__ Wp,
    const int* __restrict__ d0, const int* __restrict__ d1,
    int* __restrict__ cnt, int E, int N, int packBlocks) {
  if ((int)blockIdx.x < packBlocks) {
    int tid = blockIdx.x * 256 + threadIdx.x;  // 0..196607
    int m = tid >> 14;
    int r = tid & 16383;
    int b = r & 7, lane = (r >> 3) & 63, ks = (r >> 9) & 3, jt = r >> 11;
    int k = ks * 32 + ((lane >> 4) << 3) + b;
    int j = jt * 16 + (lane & 15);
    float w = P.w[m][k * 128 + j];
    unsigned short h = f2bf(w);
    Wp[m * 32768 + r] = h;
    Wp[m * 32768 + 16384 + r] = f2bf(w - bf2f(h));
  } else {
    int e = ((int)blockIdx.x - packBlocks) * 256 + threadIdx.x;
    if (e < E) {
      atomicAdd(&cnt[d0[e]], 1);
      atomicAdd(&cnt[N + d1[e]], 1);
    }
  }
}

// ---------------- CSR scan (concatenated: type0=[0,N), type1=[N,2N)) ----------------
__global__ __launch_bounds__(256) void scan_part_kernel(const int* __restrict__ cnt,
                                                        int* __restrict__ off,
                                                        int* __restrict__ bsum, int n2) {
  __shared__ int sh[256];
  int t = threadIdx.x;
  int i0 = blockIdx.x * 512 + 2 * t;
  int a0 = (i0 < n2) ? cnt[i0] : 0;
  int a1 = (i0 + 1 < n2) ? cnt[i0 + 1] : 0;
  int s = a0 + a1;
  sh[t] = s;
  __syncthreads();
  for (int d = 1; d < 256; d <<= 1) {
    int v = (t >= d) ? sh[t - d] : 0;
    __syncthreads();
    sh[t] += v;
    __syncthreads();
  }
  int p = sh[t] - s;
  if (i0 < n2) off[i0] = p;
  if (i0 + 1 < n2) off[i0 + 1] = p + a0;
  if (t == 255) bsum[blockIdx.x] = sh[255];
}

__global__ __launch_bounds__(256) void scan_bsum_kernel(int* __restrict__ bsum, int nb,
                                                        int* __restrict__ off_total) {
  __shared__ int sh[256];
  int t = threadIdx.x;
  int s = (t < nb) ? bsum[t] : 0;
  sh[t] = s;
  __syncthreads();
  for (int d = 1; d < 256; d <<= 1) {
    int v = (t >= d) ? sh[t - d] : 0;
    __syncthreads();
    sh[t] += v;
    __syncthreads();
  }
  if (t < nb) bsum[t] = sh[t] - s;
  if (t == 255) *off_total = sh[255];
}

__global__ __launch_bounds__(256) void scan_add_kernel(int* __restrict__ off,
                                                       const int* __restrict__ bsum,
                                                       int* __restrict__ cnt,
                                                       float* __restrict__ dinv, int n2) {
  int add = bsum[blockIdx.x];
  int base = blockIdx.x * 512;
#pragma unroll
  for (int u = 0; u < 2; u++) {
    int i = base + threadIdx.x + u * 256;
    if (i < n2) {
      off[i] += add;
      dinv[i] = rsqrtf((float)cnt[i] + 1.0f);
      cnt[i] = 0;
    }
  }
}

__global__ void fill_kernel(const int* __restrict__ ei0, const int* __restrict__ ei1,
                            const int* __restrict__ off, int* __restrict__ cnt,
                            int* __restrict__ csr, int E, int N) {
  int e = blockIdx.x * blockDim.x + threadIdx.x;
  if (e < E) {
    int s = ei0[e], d = ei0[E + e];
    int p = atomicAdd(&cnt[d], 1);
    csr[off[d] + p] = s;
    s = ei1[e]; d = ei1[E + e];
    p = atomicAdd(&cnt[N + d], 1);
    csr[off[N + d] + p] = s;
  }
}

// ---------------- split helper ----------------
__device__ __forceinline__ void split8(const float vv[8], bf16x8& hh, bf16x8& hl) {
#pragma unroll
  for (int c = 0; c < 8; c++) {
    unsigned short h = f2bf(vv[c]);
    hh[c] = (short)h;
    hl[c] = (short)f2bf(vv[c] - bf2f(h));
  }
}

// ---------------- dual GCN matmul (operand-swapped, split precision) ----------------
template <int BN>
__global__ __launch_bounds__(256) void mm_dual(
    const unsigned short* __restrict__ Wp, const float* __restrict__ Af,
    const float* __restrict__ stats, const float* __restrict__ g0,
    const float* __restrict__ bt0, const float* __restrict__ dinv,
    _Float16* __restrict__ tab0, _Float16* __restrict__ tab1,
    int n, int N, float invn) {
  __shared__ float bnsc[128], bnsh[128];
  if (BN) {
    int t = threadIdx.x;
    if (t < 128) {
      float s = 0.f, q = 0.f;
#pragma unroll
      for (int r = 0; r < 8; r++) { s += stats[r * 128 + t]; q += stats[1024 + r * 128 + t]; }
      float mu = s * invn, var = q * invn - mu * mu;
      float sc = g0[t] * rsqrtf(var + 1e-5f);
      bnsc[t] = sc; bnsh[t] = bt0[t] - mu * sc;
    }
    __syncthreads();
  }
  constexpr int WJT = 4, WIT = 4;
  const int lane = threadIdx.x & 63;
  const int wid = threadIdx.x >> 6;
  const int wj = wid % 4, wi = wid / 4;
  const int jtbase = wj * WJT;
  const int ibase = blockIdx.x * 64 + wi * WIT * 16;
  const int lrow = lane & 15, lgrp = lane >> 4;

  int node[WIT];
  bool valid[WIT];
#pragma unroll
  for (int it = 0; it < WIT; it++) {
    int i = ibase + it * 16 + lrow;
    valid[it] = (i < n);
    node[it] = valid[it] ? i : (n - 1);
  }

  f32x4 acc[WJT][WIT];
#pragma unroll
  for (int jt = 0; jt < WJT; jt++)
#pragma unroll
    for (int it = 0; it < WIT; it++) acc[jt][it] = (f32x4){0.f, 0.f, 0.f, 0.f};

#pragma unroll
  for (int ks = 0; ks < 4; ks++) {
    float sck[8], shk[8];
    if (BN) {
      int cb = ks * 32 + lgrp * 8;
#pragma unroll
      for (int c = 0; c < 8; c++) { sck[c] = bnsc[cb + c]; shk[c] = bnsh[cb + c]; }
    }
    bf16x8 awh[WJT], awl[WJT];
#pragma unroll
    for (int jt = 0; jt < WJT; jt++) {
      int jg = jtbase + jt;
      const unsigned short* base = Wp + ((jg >= 8) ? 32768 : 0);
      size_t fo = (size_t)(((jg & 7) * 4 + ks) * 64 + lane) * 8;
      awh[jt] = *(const bf16x8*)(base + fo);
      awl[jt] = *(const bf16x8*)(base + fo + 16384);
    }
#pragma unroll
    for (int it = 0; it < WIT; it++) {
      const float* src = Af + (size_t)node[it] * 128 + ks * 32 + lgrp * 8;
      float4 u0 = *(const float4*)src;
      float4 u1 = *(const float4*)(src + 4);
      float vv[8] = {u0.x, u0.y, u0.z, u0.w, u1.x, u1.y, u1.z, u1.w};
      if (BN) {
#pragma unroll
        for (int c = 0; c < 8; c++) vv[c] = fmaxf(vv[c] * sck[c] + shk[c], 0.f);
      }
      bf16x8 bhh, bhl;
      split8(vv, bhh, bhl);
#pragma unroll
      for (int jt = 0; jt < WJT; jt++) {
        acc[jt][it] = __builtin_amdgcn_mfma_f32_16x16x32_bf16(awh[jt], bhh, acc[jt][it], 0, 0, 0);
        acc[jt][it] = __builtin_amdgcn_mfma_f32_16x16x32_bf16(awl[jt], bhh, acc[jt][it], 0, 0, 0);
        acc[jt][it] = __builtin_amdgcn_mfma_f32_16x16x32_bf16(awh[jt], bhl, acc[jt][it], 0, 0, 0);
      }
    }
  }

#pragma unroll
  for (int it = 0; it < WIT; it++) {
    if (!valid[it]) continue;
    float d0v = dinv[node[it]];
    float d1v = dinv[N + node[it]];
#pragma unroll
    for (int jt = 0; jt < WJT; jt++) {
      int jg = jtbase + jt;
      float s = (jg < 8) ? d0v : d1v;
      _Float16 o[4];
#pragma unroll
      for (int c = 0; c < 4; c++) o[c] = (_Float16)(acc[jt][it][c] * s);
      _Float16* base = (jg < 8)
          ? (tab0 + (size_t)node[it] * 128 + jg * 16)
          : (tab1 + (size_t)node[it] * 128 + (jg - 8) * 16);
      *(uint2*)(base + lgrp * 4) = *(uint2*)o;
    }
  }
}

// ---------------- gather + fused BN stats ----------------
__global__ __launch_bounds__(256) void gather_kernel(
    const _Float16* __restrict__ tab0, const _Float16* __restrict__ tab1,
    const float* __restrict__ dinv, const int* __restrict__ off,
    const int* __restrict__ csr,
    const float* __restrict__ b0, const float* __restrict__ b1,
    float* __restrict__ outh, float* __restrict__ stats, int n, int N) {
  __shared__ float reds[4][128];
  __shared__ float redq[4][128];
  int t = threadIdx.x;
  int g = t >> 4, l = t & 15;
  int node = blockIdx.x * 16 + g;
  bool valid = node < n;
  int nd = valid ? node : 0;
  const f16x8* t0 = (const f16x8*)tab0;
  const f16x8* t1 = (const f16x8*)tab1;
  float s0[8] = {0,0,0,0,0,0,0,0}, s1[8] = {0,0,0,0,0,0,0,0};
  if (valid) {
    f16x8 v = t0[(size_t)nd * 16 + l];
#pragma unroll
    for (int c = 0; c < 8; c++) s0[c] = (float)v[c];
    v = t1[(size_t)nd * 16 + l];
#pragma unroll
    for (int c = 0; c < 8; c++) s1[c] = (float)v[c];
  }
  int a = valid ? off[nd] : 0, b = valid ? off[nd + 1] : 0;
  int j = a;
  for (; j + 3 < b; j += 4) {
    int i0 = csr[j], i1 = csr[j + 1], i2 = csr[j + 2], i3 = csr[j + 3];
    f16x8 v0 = t0[(size_t)i0 * 16 + l];
    f16x8 v1 = t0[(size_t)i1 * 16 + l];
    f16x8 v2 = t0[(size_t)i2 * 16 + l];
    f16x8 v3 = t0[(size_t)i3 * 16 + l];
#pragma unroll
    for (int c = 0; c < 8; c++)
      s0[c] += ((float)v0[c] + (float)v1[c]) + ((float)v2[c] + (float)v3[c]);
  }
  for (; j < b; j++) {
    f16x8 va = t0[(size_t)csr[j] * 16 + l];
#pragma unroll
    for (int c = 0; c < 8; c++) s0[c] += (float)va[c];
  }
  a = valid ? off[N + nd] : 0; b = valid ? off[N + nd + 1] : 0;
  j = a;
  for (; j + 3 < b; j += 4) {
    int i0 = csr[j], i1 = csr[j + 1], i2 = csr[j + 2], i3 = csr[j + 3];
    f16x8 v0 = t1[(size_t)i0 * 16 + l];
    f16x8 v1 = t1[(size_t)i1 * 16 + l];
    f16x8 v2 = t1[(size_t)i2 * 16 + l];
    f16x8 v3 = t1[(size_t)i3 * 16 + l];
#pragma unroll
    for (int c = 0; c < 8; c++)
      s1[c] += ((float)v0[c] + (float)v1[c]) + ((float)v2[c] + (float)v3[c]);
  }
  for (; j < b; j++) {
    f16x8 va = t1[(size_t)csr[j] * 16 + l];
#pragma unroll
    for (int c = 0; c < 8; c++) s1[c] += (float)va[c];
  }
  float o[8] = {0,0,0,0,0,0,0,0};
  if (valid) {
    float d0 = dinv[nd], d1 = dinv[N + nd];
    const float4* B0 = (const float4*)(b0 + l * 8);
    const float4* B1 = (const float4*)(b1 + l * 8);
    float4 ba0 = B0[0], ba1 = B0[1], bb0 = B1[0], bb1 = B1[1];
    float bs[8] = {ba0.x + bb0.x, ba0.y + bb0.y, ba0.z + bb0.z, ba0.w + bb0.w,
                   ba1.x + bb1.x, ba1.y + bb1.y, ba1.z + bb1.z, ba1.w + bb1.w};
#pragma unroll
    for (int c = 0; c < 8; c++) o[c] = d0 * s0[c] + d1 * s1[c] + bs[c];
    float* dst = outh + (size_t)nd * 128 + l * 8;
    *(float4*)dst = make_float4(o[0], o[1], o[2], o[3]);
    *(float4*)(dst + 4) = make_float4(o[4], o[5], o[6], o[7]);
  }
  float sv[8], q[8];
#pragma unroll
  for (int c = 0; c < 8; c++) { sv[c] = o[c]; q[c] = o[c] * o[c]; }
#pragma unroll
  for (int c = 0; c < 8; c++) {
    sv[c] += __shfl_xor(sv[c], 16); sv[c] += __shfl_xor(sv[c], 32);
    q[c] += __shfl_xor(q[c], 16);  q[c] += __shfl_xor(q[c], 32);
  }
  int lane = t & 63, wid = t >> 6;
  if (lane < 16) {
#pragma unroll
    for (int c = 0; c < 8; c++) { reds[wid][lane * 8 + c] = sv[c]; redq[wid][lane * 8 + c] = q[c]; }
  }
  __syncthreads();
  if (t < 128) {
    float ts = reds[0][t] + reds[1][t] + reds[2][t] + reds[3][t];
    float tq = redq[0][t] + redq[1][t] + redq[2][t] + redq[3][t];
    int cp = blockIdx.x & 7;
    atomicAdd(&stats[cp * 128 + t], ts);
    atomicAdd(&stats[1024 + cp * 128 + t], tq);
  }
}

// ---------------- fully-fused heads: e->t->p per head, LDS chained ----------------
// 64 nodes/block, 4 waves: wh=wid>>1 selects head, wj=wid&1 selects feature half.
// Per wave: WJT=4 (64 feats), WIT=4 (64 nodes). Stage intermediates in padded LDS.
#define TP 132  // tile row pitch (floats): 4-way max bank aliasing
__global__ __launch_bounds__(256) void heads3_kernel(
    const unsigned short* __restrict__ Wp,   // slots 6..11
    const float* __restrict__ h, const float* __restrict__ stats,
    const float* __restrict__ g2, const float* __restrict__ bt2,
    const float* __restrict__ emb1_b, const float* __restrict__ emb2_b,
    const float* __restrict__ ph1_ba, const float* __restrict__ ph1_bb,
    const float* __restrict__ ph2_ba, const float* __restrict__ ph2_bb,
    float* __restrict__ out, int n, float invn) {
  __shared__ float bnsc[128], bnsh[128];
  __shared__ float tile[2][64 * TP];
  __shared__ float l2red[2][4][16][2];
  const int t = threadIdx.x;
  if (t < 128) {
    float s = 0.f, q = 0.f;
#pragma unroll
    for (int r = 0; r < 8; r++) { s += stats[r * 128 + t]; q += stats[1024 + r * 128 + t]; }
    float mu = s * invn, var = q * invn - mu * mu;
    float sc = g2[t] * rsqrtf(var + 1e-5f);
    bnsc[t] = sc; bnsh[t] = bt2[t] - mu * sc;
  }
  __syncthreads();

  const int lane = t & 63, wid = t >> 6;
  const int wj = wid & 1, wh = wid >> 1;
  const int lrow = lane & 15, lgrp = lane >> 4;
  const int jtbase = wj * 4;
  const int base = blockIdx.x * 64;
  const size_t ND = (size_t)n * 128;
  float* myt = &tile[wh][0];

  int node[4];
  bool valid[4];
#pragma unroll
  for (int it = 0; it < 4; it++) {
    int i = base + it * 16 + lrow;
    valid[it] = (i < n);
    node[it] = valid[it] ? i : (n - 1);
  }

  f32x4 acc[4][4];
  const unsigned short* slot;
  const float* bias;

  // ======== stage 1: e = tanh(BN(h) @ W[6+wh] + emb_b) ========
  slot = Wp + (size_t)(6 + wh) * 32768;
  bias = wh ? emb2_b : emb1_b;
#pragma unroll
  for (int jt = 0; jt < 4; jt++) {
    float4 b4 = *(const float4*)(bias + (jtbase + jt) * 16 + lgrp * 4);
#pragma unroll
    for (int it = 0; it < 4; it++) acc[jt][it] = (f32x4){b4.x, b4.y, b4.z, b4.w};
  }
#pragma unroll
  for (int ks = 0; ks < 4; ks++) {
    int cb = ks * 32 + lgrp * 8;
    float sck[8], shk[8];
#pragma unroll
    for (int c = 0; c < 8; c++) { sck[c] = bnsc[cb + c]; shk[c] = bnsh[cb + c]; }
    bf16x8 awh[4], awl[4];
#pragma unroll
    for (int jt = 0; jt < 4; jt++) {
      size_t fo = (size_t)(((jtbase + jt) * 4 + ks) * 64 + lane) * 8;
      awh[jt] = *(const bf16x8*)(slot + fo);
      awl[jt] = *(const bf16x8*)(slot + fo + 16384);
    }
#pragma unroll
    for (int it = 0; it < 4; it++) {
      const float* src = h + (size_t)node[it] * 128 + cb;
      float4 u0 = *(const float4*)src;
      float4 u1 = *(const float4*)(src + 4);
      float vv[8] = {u0.x, u0.y, u0.z, u0.w, u1.x, u1.y, u1.z, u1.w};
#pragma unroll
      for (int c = 0; c < 8; c++) vv[c] = vv[c] * sck[c] + shk[c];
      bf16x8 bhh, bhl;
      split8(vv, bhh, bhl);
#pragma unroll
      for (int jt = 0; jt < 4; jt++) {
        acc[jt][it] = __builtin_amdgcn_mfma_f32_16x16x32_bf16(awh[jt], bhh, acc[jt][it], 0, 0, 0);
        acc[jt][it] = __builtin_amdgcn_mfma_f32_16x16x32_bf16(awl[jt], bhh, acc[jt][it], 0, 0, 0);
        acc[jt][it] = __builtin_amdgcn_mfma_f32_16x16x32_bf16(awh[jt], bhl, acc[jt][it], 0, 0, 0);
      }
    }
  }
#pragma unroll
  for (int jt = 0; jt < 4; jt++)
#pragma unroll
    for (int it = 0; it < 4; it++)
#pragma unroll
      for (int c = 0; c < 4; c++) acc[jt][it][c] = fast_tanh(acc[jt][it][c]);

  // e2 l2norm (head 1 only)
  float rsv[4];
  if (wh == 1) {
#pragma unroll
    for (int it = 0; it < 4; it++) {
      float rs = 0.f;
#pragma unroll
      for (int jt = 0; jt < 4; jt++)
#pragma unroll
        for (int c = 0; c < 4; c++) rs += acc[jt][it][c] * acc[jt][it][c];
      rs += __shfl_xor(rs, 16);
      rs += __shfl_xor(rs, 32);
      rsv[it] = rs;
      if (lane < 16) l2red[1][it][lane][wj] = rs;
    }
  }
  __syncthreads();
  if (wh == 1) {
#pragma unroll
    for (int it = 0; it < 4; it++) {
      float full = rsv[it] + l2red[1][it][lrow][wj ^ 1];
      float scl = 1.f / fmaxf(sqrtf(full), 1e-12f);
#pragma unroll
      for (int jt = 0; jt < 4; jt++)
#pragma unroll
        for (int c = 0; c < 4; c++) acc[jt][it][c] *= scl;
    }
  }
  // write e to LDS tile + global out[wh]
#pragma unroll
  for (int it = 0; it < 4; it++) {
#pragma unroll
    for (int jt = 0; jt < 4; jt++) {
      float4 v = make_float4(acc[jt][it][0], acc[jt][it][1], acc[jt][it][2], acc[jt][it][3]);
      *(float4*)(myt + (it * 16 + lrow) * TP + (jtbase + jt) * 16 + lgrp * 4) = v;
      if (valid[it])
        *(float4*)(out + (size_t)wh * ND + (size_t)node[it] * 128 + (jtbase + jt) * 16 + lgrp * 4) = v;
    }
  }
  __syncthreads();

  // ======== stage 2: t = relu(e @ W[8+2wh] + ph_ba) ========
  slot = Wp + (size_t)(8 + 2 * wh) * 32768;
  bias = wh ? ph2_ba : ph1_ba;
#pragma unroll
  for (int jt = 0; jt < 4; jt++) {
    float4 b4 = *(const float4*)(bias + (jtbase + jt) * 16 + lgrp * 4);
#pragma unroll
    for (int it = 0; it < 4; it++) acc[jt][it] = (f32x4){b4.x, b4.y, b4.z, b4.w};
  }
#pragma unroll
  for (int ks = 0; ks < 4; ks++) {
    bf16x8 awh[4], awl[4];
#pragma unroll
    for (int jt = 0; jt < 4; jt++) {
      size_t fo = (size_t)(((jtbase + jt) * 4 + ks) * 64 + lane) * 8;
      awh[jt] = *(const bf16x8*)(slot + fo);
      awl[jt] = *(const bf16x8*)(slot + fo + 16384);
    }
#pragma unroll
    for (int it = 0; it < 4; it++) {
      const float* src = myt + (it * 16 + lrow) * TP + ks * 32 + lgrp * 8;
      float4 u0 = *(const float4*)src;
      float4 u1 = *(const float4*)(src + 4);
      float vv[8] = {u0.x, u0.y, u0.z, u0.w, u1.x, u1.y, u1.z, u1.w};
      bf16x8 bhh, bhl;
      split8(vv, bhh, bhl);
#pragma unroll
      for (int jt = 0; jt < 4; jt++) {
        acc[jt][it] = __builtin_amdgcn_mfma_f32_16x16x32_bf16(awh[jt], bhh, acc[jt][it], 0, 0, 0);
        acc[jt][it] = __builtin_amdgcn_mfma_f32_16x16x32_bf16(awl[jt], bhh, acc[jt][it], 0, 0, 0);
        acc[jt][it] = __builtin_amdgcn_mfma_f32_16x16x32_bf16(awh[jt], bhl, acc[jt][it], 0, 0, 0);
      }
    }
  }
#pragma unroll
  for (int jt = 0; jt < 4; jt++)
#pragma unroll
    for (int it = 0; it < 4; it++)
#pragma unroll
      for (int c = 0; c < 4; c++) acc[jt][it][c] = fmaxf(acc[jt][it][c], 0.f);
  __syncthreads();  // everyone done reading e tiles
#pragma unroll
  for (int it = 0; it < 4; it++)
#pragma unroll
    for (int jt = 0; jt < 4; jt++)
      *(float4*)(myt + (it * 16 + lrow) * TP + (jtbase + jt) * 16 + lgrp * 4) =
          make_float4(acc[jt][it][0], acc[jt][it][1], acc[jt][it][2], acc[jt][it][3]);
  __syncthreads();

  // ======== stage 3: p = l2norm(t @ W[9+2wh] + ph_bb) ========
  slot = Wp + (size_t)(9 + 2 * wh) * 32768;
  bias = wh ? ph2_bb : ph1_bb;
#pragma unroll
  for (int jt = 0; jt < 4; jt++) {
    float4 b4 = *(const float4*)(bias + (jtbase + jt) * 16 + lgrp * 4);
#pragma unroll
    for (int it = 0; it < 4; it++) acc[jt][it] = (f32x4){b4.x, b4.y, b4.z, b4.w};
  }
#pragma unroll
  for (int ks = 0; ks < 4; ks++) {
    bf16x8 awh[4], awl[4];
#pragma unroll
    for (int jt = 0; jt < 4; jt++) {
      size_t fo = (size_t)(((jtbase + jt) * 4 + ks) * 64 + lane) * 8;
      awh[jt] = *(const bf16x8*)(slot + fo);
      awl[jt] = *(const bf16x8*)(slot + fo + 16384);
    }
#pragma unroll
    for (int it = 0; it < 4; it++) {
      const float* src = myt + (it * 16 + lrow) * TP + ks * 32 + lgrp * 8;
      float4 u0 = *(const float4*)src;
      float4 u1 = *(const float4*)(src + 4);
      float vv[8] = {u0.x, u0.y, u0.z, u0.w, u1.x, u1.y, u1.z, u1.w};
      bf16x8 bhh, bhl;
      split8(vv, bhh, bhl);
#pragma unroll
      for (int jt = 0; jt < 4; jt++) {
        acc[jt][it] = __builtin_amdgcn_mfma_f32_16x16x32_bf16(awh[jt], bhh, acc[jt][it], 0, 0, 0);
        acc[jt][it] = __builtin_amdgcn_mfma_f32_16x16x32_bf16(awl[jt], bhh, acc[jt][it], 0, 0, 0);
        acc[jt][it] = __builtin_amdgcn_mfma_f32_16x16x32_bf16(awh[jt], bhl, acc[jt][it], 0, 0, 0);
      }
    }
  }
#pragma unroll
  for (int it = 0; it < 4; it++) {
    float rs = 0.f;
#pragma unroll
    for (int jt = 0; jt < 4; jt++)
#pragma unroll
      for (int c = 0; c < 4; c++) rs += acc[jt][it][c] * acc[jt][it][c];
    rs += __shfl_xor(rs, 16);
    rs += __shfl_xor(rs, 32);
    rsv[it] = rs;
    if (lane < 16) l2red[wh][it][lane][wj] = rs;
  }
  __syncthreads();
#pragma unroll
  for (int it = 0; it < 4; it++) {
    float full = rsv[it] + l2red[wh][it][lrow][wj ^ 1];
    float scl = 1.f / fmaxf(sqrtf(full), 1e-12f);
    if (!valid[it]) continue;
#pragma unroll
    for (int jt = 0; jt < 4; jt++)
      *(float4*)(out + (size_t)(2 + wh) * ND + (size_t)node[it] * 128 + (jtbase + jt) * 16 + lgrp * 4) =
          make_float4(acc[jt][it][0] * scl, acc[jt][it][1] * scl,
                      acc[jt][it][2] * scl, acc[jt][it][3] * scl);
  }
}

// ---------------- launch ----------------
extern "C" void kernel_launch(void* const* d_in, const int* in_sizes, int n_in,
                              void* d_out, int out_size, void* d_ws, size_t ws_size,
                              hipStream_t stream) {
  const float* x      = (const float*)d_in[0];
  const int*   ei0    = (const int*)d_in[1];
  const int*   ei1    = (const int*)d_in[2];
  const float* W0     = (const float*)d_in[3];
  const float* b0     = (const float*)d_in[4];
  const float* W1     = (const float*)d_in[5];
  const float* b1     = (const float*)d_in[6];
  const float* gamma  = (const float*)d_in[7];
  const float* beta   = (const float*)d_in[8];
  const float* emb1_W = (const float*)d_in[9];
  const float* emb1_b = (const float*)d_in[10];
  const float* emb2_W = (const float*)d_in[11];
  const float* emb2_b = (const float*)d_in[12];
  const float* ph1_Wa = (const float*)d_in[13];
  const float* ph1_ba = (const float*)d_in[14];
  const float* ph1_Wb = (const float*)d_in[15];
  const float* ph1_bb = (const float*)d_in[16];
  const float* ph2_Wa = (const float*)d_in[17];
  const float* ph2_ba = (const float*)d_in[18];
  const float* ph2_Wb = (const float*)d_in[19];
  const float* ph2_bb = (const float*)d_in[20];

  const int N = in_sizes[0] / D;
  const int E = in_sizes[1] / 2;
  const int N2 = 2 * N;
  const size_t ND = (size_t)N * D;
  const float invn = 1.0f / (float)N;
  float* out = (float*)d_out;

  char* p = (char*)d_ws;
  auto carve = [&](size_t bytes) -> void* {
    void* r = (void*)p;
    p += (bytes + 255) & ~(size_t)255;
    return r;
  };
  // cnt + 3-layer stats carved contiguously -> single memset zeroes both
  int*   cnt   = (int*)carve((size_t)N2 * 4);
  float* stats = (float*)carve((size_t)3 * 2048 * 4);   // [layer][2][8][128]
  size_t zbytes = (size_t)((char*)(stats + 3 * 2048) - (char*)cnt);
  int*   off   = (int*)carve((size_t)(N2 + 1) * 4);
  float* dinv  = (float*)carve((size_t)N2 * 4);
  int*   csr   = (int*)carve((size_t)2 * E * 4);
  int*   bsum  = (int*)carve(256 * 4);
  unsigned short* Wp = (unsigned short*)carve((size_t)12 * 32768 * 2);
  float* hbuf = (float*)carve(4 * ND);
  _Float16* tab0 = (_Float16*)carve(2 * ND);
  _Float16* tab1 = (_Float16*)carve(2 * ND);

  const int TPB = 256;
  const int packBlocks = 768;
  const int gridPC = packBlocks + (E + TPB - 1) / TPB;
  const int gridE = (E + TPB - 1) / TPB;
  const int nbScan = (N2 + 511) / 512;
  const int gridDual = (N + 63) / 64;
  const int gridGath = (N + 15) / 16;
  const int gridH3 = (N + 63) / 64;

  WPtrs P;
  P.w[0] = W0;                     P.w[1] = W1;
  P.w[2] = W0 + (size_t)D * D;     P.w[3] = W1 + (size_t)D * D;
  P.w[4] = W0 + (size_t)2 * D * D; P.w[5] = W1 + (size_t)2 * D * D;
  P.w[6] = emb1_W; P.w[7] = emb2_W;
  P.w[8] = ph1_Wa; P.w[9] = ph1_Wb;
  P.w[10] = ph2_Wa; P.w[11] = ph2_Wb;

  hipMemsetAsync(cnt, 0, zbytes, stream);
  packcount_kernel<<<gridPC, TPB, 0, stream>>>(P, Wp, ei0 + E, ei1 + E, cnt, E, N, packBlocks);
  scan_part_kernel<<<nbScan, TPB, 0, stream>>>(cnt, off, bsum, N2);
  scan_bsum_kernel<<<1, TPB, 0, stream>>>(bsum, nbScan, off + N2);
  scan_add_kernel<<<nbScan, TPB, 0, stream>>>(off, bsum, cnt, dinv, N2);
  fill_kernel<<<gridE, TPB, 0, stream>>>(ei0, ei1, off, cnt, csr, E, N);

  for (int i = 0; i < 3; i++) {
    const unsigned short* wslot = Wp + (size_t)(2 * i) * 32768;
    if (i == 0) {
      mm_dual<0><<<gridDual, TPB, 0, stream>>>(wslot, x, nullptr, nullptr, nullptr,
                                               dinv, tab0, tab1, N, N, invn);
    } else {
      mm_dual<1><<<gridDual, TPB, 0, stream>>>(wslot, hbuf, stats + (size_t)(i - 1) * 2048,
                                               gamma + (i - 1) * D, beta + (i - 1) * D,
                                               dinv, tab0, tab1, N, N, invn);
    }
    gather_kernel<<<gridGath, TPB, 0, stream>>>(tab0, tab1, dinv, off, csr,
                                                b0 + i * D, b1 + i * D, hbuf,
                                                stats + (size_t)i * 2048, N, N);
  }

  heads3_kernel<<<gridH3, TPB, 0, stream>>>(
      Wp, hbuf, stats + (size_t)2 * 2048, gamma + 2 * D, beta + 2 * D,
      emb1_b, emb2_b, ph1_ba, ph1_bb, ph2_ba, ph2_bb, out, N, invn);
}

// Round 9
// 329.072 us; speedup vs baseline: 1.2709x; 1.0589x over previous
//
#include <hip/hip_runtime.h>
#include <cstdint>
#include <cstddef>

#define D 128

typedef __attribute__((ext_vector_type(8))) short bf16x8;
typedef __attribute__((ext_vector_type(4))) float f32x4;
typedef __attribute__((ext_vector_type(8))) _Float16 f16x8;

__device__ __forceinline__ unsigned short f2bf(float f) {
  unsigned int u = __float_as_uint(f);
  unsigned int r = u + 0x7FFFu + ((u >> 16) & 1u);
  return (unsigned short)(r >> 16);
}
__device__ __forceinline__ float bf2f(unsigned short h) {
  return __uint_as_float((unsigned int)h << 16);
}
__device__ __forceinline__ float fast_tanh(float x) {
  float cx = fminf(fmaxf(x, -15.f), 15.f);
  float e = __expf(2.f * cx);
  return (e - 1.f) * __builtin_amdgcn_rcpf(e + 1.f);
}
union HU { _Float16 f; unsigned short u; };

// ---------------- fused pack (12 weight mats) + degree count ----------------
// slots 0..7: bf16 hi at Wp[m*32768+r], bf16 lo at +16384
// slots 8..11: f16 hi / f16 lo (same layout)  [head stage-2/3 weights]
// r=((jt*4+ks)*64+lane)*8+b -> W[(ks*32+(lane>>4)*8+b)*128 + jt*16+(lane&15)]
struct WPtrs { const float* w[12]; };

__global__ __launch_bounds__(256) void packcount_kernel(
    WPtrs P, unsigned short* __restrict__ Wp,
    const int* __restrict__ d0, const int* __restrict__ d1,
    int* __restrict__ cnt, int E, int N, int packBlocks) {
  if ((int)blockIdx.x < packBlocks) {
    int tid = blockIdx.x * 256 + threadIdx.x;  // 0..196607
    int m = tid >> 14;
    int r = tid & 16383;
    int b = r & 7, lane = (r >> 3) & 63, ks = (r >> 9) & 3, jt = r >> 11;
    int k = ks * 32 + ((lane >> 4) << 3) + b;
    int j = jt * 16 + (lane & 15);
    float w = P.w[m][k * 128 + j];
    if (m < 8) {
      unsigned short h = f2bf(w);
      Wp[m * 32768 + r] = h;
      Wp[m * 32768 + 16384 + r] = f2bf(w - bf2f(h));
    } else {
      HU hh, ll;
      hh.f = (_Float16)w;
      ll.f = (_Float16)(w - (float)hh.f);
      Wp[m * 32768 + r] = hh.u;
      Wp[m * 32768 + 16384 + r] = ll.u;
    }
  } else {
    int e = ((int)blockIdx.x - packBlocks) * 256 + threadIdx.x;
    if (e < E) {
      atomicAdd(&cnt[d0[e]], 1);
      atomicAdd(&cnt[N + d1[e]], 1);
    }
  }
}

// ---------------- CSR scan (concatenated: type0=[0,N), type1=[N,2N)) ----------------
__global__ __launch_bounds__(256) void scan_part_kernel(const int* __restrict__ cnt,
                                                        int* __restrict__ off,
                                                        int* __restrict__ bsum, int n2) {
  __shared__ int sh[256];
  int t = threadIdx.x;
  int i0 = blockIdx.x * 512 + 2 * t;
  int a0 = (i0 < n2) ? cnt[i0] : 0;
  int a1 = (i0 + 1 < n2) ? cnt[i0 + 1] : 0;
  int s = a0 + a1;
  sh[t] = s;
  __syncthreads();
  for (int d = 1; d < 256; d <<= 1) {
    int v = (t >= d) ? sh[t - d] : 0;
    __syncthreads();
    sh[t] += v;
    __syncthreads();
  }
  int p = sh[t] - s;
  if (i0 < n2) off[i0] = p;
  if (i0 + 1 < n2) off[i0 + 1] = p + a0;
  if (t == 255) bsum[blockIdx.x] = sh[255];
}

__global__ __launch_bounds__(256) void scan_bsum_kernel(int* __restrict__ bsum, int nb,
                                                        int* __restrict__ off_total) {
  __shared__ int sh[256];
  int t = threadIdx.x;
  int s = (t < nb) ? bsum[t] : 0;
  sh[t] = s;
  __syncthreads();
  for (int d = 1; d < 256; d <<= 1) {
    int v = (t >= d) ? sh[t - d] : 0;
    __syncthreads();
    sh[t] += v;
    __syncthreads();
  }
  if (t < nb) bsum[t] = sh[t] - s;
  if (t == 255) *off_total = sh[255];
}

__global__ __launch_bounds__(256) void scan_add_kernel(int* __restrict__ off,
                                                       const int* __restrict__ bsum,
                                                       int* __restrict__ cnt,
                                                       float* __restrict__ dinv, int n2) {
  int add = bsum[blockIdx.x];
  int base = blockIdx.x * 512;
#pragma unroll
  for (int u = 0; u < 2; u++) {
    int i = base + threadIdx.x + u * 256;
    if (i < n2) {
      off[i] += add;
      dinv[i] = rsqrtf((float)cnt[i] + 1.0f);
      cnt[i] = 0;
    }
  }
}

// ---------------- split helper ----------------
__device__ __forceinline__ void split8(const float vv[8], bf16x8& hh, bf16x8& hl) {
#pragma unroll
  for (int c = 0; c < 8; c++) {
    unsigned short h = f2bf(vv[c]);
    hh[c] = (short)h;
    hl[c] = (short)f2bf(vv[c] - bf2f(h));
  }
}

// ---------------- dual GCN matmul body (operand-swapped, split precision) ----------------
template <int BN>
__device__ __forceinline__ void mm_dual_body(
    int bid, const unsigned short* __restrict__ Wp, const float* __restrict__ Af,
    const float* __restrict__ stats, const float* __restrict__ g0,
    const float* __restrict__ bt0, const float* __restrict__ dinv,
    _Float16* __restrict__ tab0, _Float16* __restrict__ tab1,
    int n, int N, float invn) {
  __shared__ float bnsc[128], bnsh[128];
  if (BN) {
    int t = threadIdx.x;
    if (t < 128) {
      float s = 0.f, q = 0.f;
#pragma unroll
      for (int r = 0; r < 8; r++) { s += stats[r * 128 + t]; q += stats[1024 + r * 128 + t]; }
      float mu = s * invn, var = q * invn - mu * mu;
      float sc = g0[t] * rsqrtf(var + 1e-5f);
      bnsc[t] = sc; bnsh[t] = bt0[t] - mu * sc;
    }
    __syncthreads();
  }
  constexpr int WJT = 4, WIT = 4;
  const int lane = threadIdx.x & 63;
  const int wid = threadIdx.x >> 6;
  const int wj = wid % 4, wi = wid / 4;
  const int jtbase = wj * WJT;
  const int ibase = bid * 64 + wi * WIT * 16;
  const int lrow = lane & 15, lgrp = lane >> 4;

  int node[WIT];
  bool valid[WIT];
#pragma unroll
  for (int it = 0; it < WIT; it++) {
    int i = ibase + it * 16 + lrow;
    valid[it] = (i < n);
    node[it] = valid[it] ? i : (n - 1);
  }

  f32x4 acc[WJT][WIT];
#pragma unroll
  for (int jt = 0; jt < WJT; jt++)
#pragma unroll
    for (int it = 0; it < WIT; it++) acc[jt][it] = (f32x4){0.f, 0.f, 0.f, 0.f};

#pragma unroll
  for (int ks = 0; ks < 4; ks++) {
    float sck[8], shk[8];
    if (BN) {
      int cb = ks * 32 + lgrp * 8;
#pragma unroll
      for (int c = 0; c < 8; c++) { sck[c] = bnsc[cb + c]; shk[c] = bnsh[cb + c]; }
    }
    bf16x8 awh[WJT], awl[WJT];
#pragma unroll
    for (int jt = 0; jt < WJT; jt++) {
      int jg = jtbase + jt;
      const unsigned short* base = Wp + ((jg >= 8) ? 32768 : 0);
      size_t fo = (size_t)(((jg & 7) * 4 + ks) * 64 + lane) * 8;
      awh[jt] = *(const bf16x8*)(base + fo);
      awl[jt] = *(const bf16x8*)(base + fo + 16384);
    }
#pragma unroll
    for (int it = 0; it < WIT; it++) {
      const float* src = Af + (size_t)node[it] * 128 + ks * 32 + lgrp * 8;
      float4 u0 = *(const float4*)src;
      float4 u1 = *(const float4*)(src + 4);
      float vv[8] = {u0.x, u0.y, u0.z, u0.w, u1.x, u1.y, u1.z, u1.w};
      if (BN) {
#pragma unroll
        for (int c = 0; c < 8; c++) vv[c] = fmaxf(vv[c] * sck[c] + shk[c], 0.f);
      }
      bf16x8 bhh, bhl;
      split8(vv, bhh, bhl);
#pragma unroll
      for (int jt = 0; jt < WJT; jt++) {
        acc[jt][it] = __builtin_amdgcn_mfma_f32_16x16x32_bf16(awh[jt], bhh, acc[jt][it], 0, 0, 0);
        acc[jt][it] = __builtin_amdgcn_mfma_f32_16x16x32_bf16(awl[jt], bhh, acc[jt][it], 0, 0, 0);
        acc[jt][it] = __builtin_amdgcn_mfma_f32_16x16x32_bf16(awh[jt], bhl, acc[jt][it], 0, 0, 0);
      }
    }
  }

#pragma unroll
  for (int it = 0; it < WIT; it++) {
    if (!valid[it]) continue;
    float d0v = dinv[node[it]];
    float d1v = dinv[N + node[it]];
#pragma unroll
    for (int jt = 0; jt < WJT; jt++) {
      int jg = jtbase + jt;
      float s = (jg < 8) ? d0v : d1v;
      _Float16 o[4];
#pragma unroll
      for (int c = 0; c < 4; c++) o[c] = (_Float16)(acc[jt][it][c] * s);
      _Float16* base = (jg < 8)
          ? (tab0 + (size_t)node[it] * 128 + jg * 16)
          : (tab1 + (size_t)node[it] * 128 + (jg - 8) * 16);
      *(uint2*)(base + lgrp * 4) = *(uint2*)o;
    }
  }
}

__global__ __launch_bounds__(256) void mm_dual_k(
    const unsigned short* __restrict__ Wp, const float* __restrict__ Af,
    const float* __restrict__ stats, const float* __restrict__ g0,
    const float* __restrict__ bt0, const float* __restrict__ dinv,
    _Float16* __restrict__ tab0, _Float16* __restrict__ tab1,
    int n, int N, float invn) {
  mm_dual_body<1>(blockIdx.x, Wp, Af, stats, g0, bt0, dinv, tab0, tab1, n, N, invn);
}

// fused: CSR fill (blocks [0,fillBlocks)) + layer-0 mm_dual (no BN)
__global__ __launch_bounds__(256) void fillmm0_kernel(
    const int* __restrict__ ei0, const int* __restrict__ ei1,
    const int* __restrict__ off, int* __restrict__ cnt, int* __restrict__ csr,
    int E, int fillBlocks,
    const unsigned short* __restrict__ Wp, const float* __restrict__ x,
    const float* __restrict__ dinv, _Float16* __restrict__ tab0,
    _Float16* __restrict__ tab1, int n, int N) {
  if ((int)blockIdx.x < fillBlocks) {
    int e = blockIdx.x * 256 + threadIdx.x;
    if (e < E) {
      int s = ei0[e], d = ei0[E + e];
      int p = atomicAdd(&cnt[d], 1);
      csr[off[d] + p] = s;
      s = ei1[e]; d = ei1[E + e];
      p = atomicAdd(&cnt[N + d], 1);
      csr[off[N + d] + p] = s;
    }
  } else {
    mm_dual_body<0>(blockIdx.x - fillBlocks, Wp, x, nullptr, nullptr, nullptr,
                    dinv, tab0, tab1, n, N, 0.f);
  }
}

// ---------------- gather + fused BN stats ----------------
__global__ __launch_bounds__(256) void gather_kernel(
    const _Float16* __restrict__ tab0, const _Float16* __restrict__ tab1,
    const float* __restrict__ dinv, const int* __restrict__ off,
    const int* __restrict__ csr,
    const float* __restrict__ b0, const float* __restrict__ b1,
    float* __restrict__ outh, float* __restrict__ stats, int n, int N) {
  __shared__ float reds[4][128];
  __shared__ float redq[4][128];
  int t = threadIdx.x;
  int g = t >> 4, l = t & 15;
  int node = blockIdx.x * 16 + g;
  bool valid = node < n;
  int nd = valid ? node : 0;
  const f16x8* t0 = (const f16x8*)tab0;
  const f16x8* t1 = (const f16x8*)tab1;
  float s0[8] = {0,0,0,0,0,0,0,0}, s1[8] = {0,0,0,0,0,0,0,0};
  if (valid) {
    f16x8 v = t0[(size_t)nd * 16 + l];
#pragma unroll
    for (int c = 0; c < 8; c++) s0[c] = (float)v[c];
    v = t1[(size_t)nd * 16 + l];
#pragma unroll
    for (int c = 0; c < 8; c++) s1[c] = (float)v[c];
  }
  int a = valid ? off[nd] : 0, b = valid ? off[nd + 1] : 0;
  int j = a;
  for (; j + 3 < b; j += 4) {
    int i0 = csr[j], i1 = csr[j + 1], i2 = csr[j + 2], i3 = csr[j + 3];
    f16x8 v0 = t0[(size_t)i0 * 16 + l];
    f16x8 v1 = t0[(size_t)i1 * 16 + l];
    f16x8 v2 = t0[(size_t)i2 * 16 + l];
    f16x8 v3 = t0[(size_t)i3 * 16 + l];
#pragma unroll
    for (int c = 0; c < 8; c++)
      s0[c] += ((float)v0[c] + (float)v1[c]) + ((float)v2[c] + (float)v3[c]);
  }
  for (; j < b; j++) {
    f16x8 va = t0[(size_t)csr[j] * 16 + l];
#pragma unroll
    for (int c = 0; c < 8; c++) s0[c] += (float)va[c];
  }
  a = valid ? off[N + nd] : 0; b = valid ? off[N + nd + 1] : 0;
  j = a;
  for (; j + 3 < b; j += 4) {
    int i0 = csr[j], i1 = csr[j + 1], i2 = csr[j + 2], i3 = csr[j + 3];
    f16x8 v0 = t1[(size_t)i0 * 16 + l];
    f16x8 v1 = t1[(size_t)i1 * 16 + l];
    f16x8 v2 = t1[(size_t)i2 * 16 + l];
    f16x8 v3 = t1[(size_t)i3 * 16 + l];
#pragma unroll
    for (int c = 0; c < 8; c++)
      s1[c] += ((float)v0[c] + (float)v1[c]) + ((float)v2[c] + (float)v3[c]);
  }
  for (; j < b; j++) {
    f16x8 va = t1[(size_t)csr[j] * 16 + l];
#pragma unroll
    for (int c = 0; c < 8; c++) s1[c] += (float)va[c];
  }
  float o[8] = {0,0,0,0,0,0,0,0};
  if (valid) {
    float d0 = dinv[nd], d1 = dinv[N + nd];
    const float4* B0 = (const float4*)(b0 + l * 8);
    const float4* B1 = (const float4*)(b1 + l * 8);
    float4 ba0 = B0[0], ba1 = B0[1], bb0 = B1[0], bb1 = B1[1];
    float bs[8] = {ba0.x + bb0.x, ba0.y + bb0.y, ba0.z + bb0.z, ba0.w + bb0.w,
                   ba1.x + bb1.x, ba1.y + bb1.y, ba1.z + bb1.z, ba1.w + bb1.w};
#pragma unroll
    for (int c = 0; c < 8; c++) o[c] = d0 * s0[c] + d1 * s1[c] + bs[c];
    float* dst = outh + (size_t)nd * 128 + l * 8;
    *(float4*)dst = make_float4(o[0], o[1], o[2], o[3]);
    *(float4*)(dst + 4) = make_float4(o[4], o[5], o[6], o[7]);
  }
  float sv[8], q[8];
#pragma unroll
  for (int c = 0; c < 8; c++) { sv[c] = o[c]; q[c] = o[c] * o[c]; }
#pragma unroll
  for (int c = 0; c < 8; c++) {
    sv[c] += __shfl_xor(sv[c], 16); sv[c] += __shfl_xor(sv[c], 32);
    q[c] += __shfl_xor(q[c], 16);  q[c] += __shfl_xor(q[c], 32);
  }
  int lane = t & 63, wid = t >> 6;
  if (lane < 16) {
#pragma unroll
    for (int c = 0; c < 8; c++) { reds[wid][lane * 8 + c] = sv[c]; redq[wid][lane * 8 + c] = q[c]; }
  }
  __syncthreads();
  if (t < 128) {
    float ts = reds[0][t] + reds[1][t] + reds[2][t] + reds[3][t];
    float tq = redq[0][t] + redq[1][t] + redq[2][t] + redq[3][t];
    int cp = blockIdx.x & 7;
    atomicAdd(&stats[cp * 128 + t], ts);
    atomicAdd(&stats[1024 + cp * 128 + t], tq);
  }
}

// ---------------- fully-fused heads: e->t->p per head, f16 LDS tiles ----------------
// 64 nodes/block, 4 waves: wh=head, wj=feature half; WJT=4, WIT=4.
// Stage 1 in bf16-split (slots 6,7); stages 2-3 in f16 hi/lo weights (slots 8-11),
// intermediates staged as f16 -> LDS ~36 KB -> 4 blocks/CU.
#define TPH 136  // f16 tile row pitch
__global__ __launch_bounds__(256) void heads3_kernel(
    const unsigned short* __restrict__ Wp,
    const float* __restrict__ h, const float* __restrict__ stats,
    const float* __restrict__ g2, const float* __restrict__ bt2,
    const float* __restrict__ emb1_b, const float* __restrict__ emb2_b,
    const float* __restrict__ ph1_ba, const float* __restrict__ ph1_bb,
    const float* __restrict__ ph2_ba, const float* __restrict__ ph2_bb,
    float* __restrict__ out, int n, float invn) {
  __shared__ float bnsc[128], bnsh[128];
  __shared__ _Float16 tile[2][64 * TPH];
  __shared__ float l2red[2][4][16][2];
  const int t = threadIdx.x;
  if (t < 128) {
    float s = 0.f, q = 0.f;
#pragma unroll
    for (int r = 0; r < 8; r++) { s += stats[r * 128 + t]; q += stats[1024 + r * 128 + t]; }
    float mu = s * invn, var = q * invn - mu * mu;
    float sc = g2[t] * rsqrtf(var + 1e-5f);
    bnsc[t] = sc; bnsh[t] = bt2[t] - mu * sc;
  }
  __syncthreads();

  const int lane = t & 63, wid = t >> 6;
  const int wj = wid & 1, wh = wid >> 1;
  const int lrow = lane & 15, lgrp = lane >> 4;
  const int jtbase = wj * 4;
  const int base = blockIdx.x * 64;
  const size_t ND = (size_t)n * 128;
  _Float16* myt = &tile[wh][0];

  int node[4];
  bool valid[4];
#pragma unroll
  for (int it = 0; it < 4; it++) {
    int i = base + it * 16 + lrow;
    valid[it] = (i < n);
    node[it] = valid[it] ? i : (n - 1);
  }

  f32x4 acc[4][4];
  const unsigned short* slot;
  const float* bias;

  // ======== stage 1: e = tanh(BN(h) @ W[6+wh] + emb_b)  (bf16 split) ========
  slot = Wp + (size_t)(6 + wh) * 32768;
  bias = wh ? emb2_b : emb1_b;
#pragma unroll
  for (int jt = 0; jt < 4; jt++) {
    float4 b4 = *(const float4*)(bias + (jtbase + jt) * 16 + lgrp * 4);
#pragma unroll
    for (int it = 0; it < 4; it++) acc[jt][it] = (f32x4){b4.x, b4.y, b4.z, b4.w};
  }
#pragma unroll
  for (int ks = 0; ks < 4; ks++) {
    int cb = ks * 32 + lgrp * 8;
    float sck[8], shk[8];
#pragma unroll
    for (int c = 0; c < 8; c++) { sck[c] = bnsc[cb + c]; shk[c] = bnsh[cb + c]; }
    bf16x8 awh[4], awl[4];
#pragma unroll
    for (int jt = 0; jt < 4; jt++) {
      size_t fo = (size_t)(((jtbase + jt) * 4 + ks) * 64 + lane) * 8;
      awh[jt] = *(const bf16x8*)(slot + fo);
      awl[jt] = *(const bf16x8*)(slot + fo + 16384);
    }
#pragma unroll
    for (int it = 0; it < 4; it++) {
      const float* src = h + (size_t)node[it] * 128 + cb;
      float4 u0 = *(const float4*)src;
      float4 u1 = *(const float4*)(src + 4);
      float vv[8] = {u0.x, u0.y, u0.z, u0.w, u1.x, u1.y, u1.z, u1.w};
#pragma unroll
      for (int c = 0; c < 8; c++) vv[c] = vv[c] * sck[c] + shk[c];
      bf16x8 bhh, bhl;
      split8(vv, bhh, bhl);
#pragma unroll
      for (int jt = 0; jt < 4; jt++) {
        acc[jt][it] = __builtin_amdgcn_mfma_f32_16x16x32_bf16(awh[jt], bhh, acc[jt][it], 0, 0, 0);
        acc[jt][it] = __builtin_amdgcn_mfma_f32_16x16x32_bf16(awl[jt], bhh, acc[jt][it], 0, 0, 0);
        acc[jt][it] = __builtin_amdgcn_mfma_f32_16x16x32_bf16(awh[jt], bhl, acc[jt][it], 0, 0, 0);
      }
    }
  }
#pragma unroll
  for (int jt = 0; jt < 4; jt++)
#pragma unroll
    for (int it = 0; it < 4; it++)
#pragma unroll
      for (int c = 0; c < 4; c++) acc[jt][it][c] = fast_tanh(acc[jt][it][c]);

  float rsv[4];
  if (wh == 1) {  // e2 l2norm
#pragma unroll
    for (int it = 0; it < 4; it++) {
      float rs = 0.f;
#pragma unroll
      for (int jt = 0; jt < 4; jt++)
#pragma unroll
        for (int c = 0; c < 4; c++) rs += acc[jt][it][c] * acc[jt][it][c];
      rs += __shfl_xor(rs, 16);
      rs += __shfl_xor(rs, 32);
      rsv[it] = rs;
      if (lane < 16) l2red[1][it][lane][wj] = rs;
    }
  }
  __syncthreads();
  if (wh == 1) {
#pragma unroll
    for (int it = 0; it < 4; it++) {
      float full = rsv[it] + l2red[1][it][lrow][wj ^ 1];
      float scl = 1.f / fmaxf(sqrtf(full), 1e-12f);
#pragma unroll
      for (int jt = 0; jt < 4; jt++)
#pragma unroll
        for (int c = 0; c < 4; c++) acc[jt][it][c] *= scl;
    }
  }
  // write e: global fp32 + f16 tile
#pragma unroll
  for (int it = 0; it < 4; it++) {
#pragma unroll
    for (int jt = 0; jt < 4; jt++) {
      if (valid[it])
        *(float4*)(out + (size_t)wh * ND + (size_t)node[it] * 128 + (jtbase + jt) * 16 + lgrp * 4) =
            make_float4(acc[jt][it][0], acc[jt][it][1], acc[jt][it][2], acc[jt][it][3]);
      _Float16 o4[4];
#pragma unroll
      for (int c = 0; c < 4; c++) o4[c] = (_Float16)acc[jt][it][c];
      *(uint2*)(myt + (it * 16 + lrow) * TPH + (jtbase + jt) * 16 + lgrp * 4) = *(uint2*)o4;
    }
  }
  __syncthreads();

  // ======== stage 2: t = relu(e @ W[8+2wh] + ph_ba)  (f16 hi/lo) ========
  slot = Wp + (size_t)(8 + 2 * wh) * 32768;
  bias = wh ? ph2_ba : ph1_ba;
#pragma unroll
  for (int jt = 0; jt < 4; jt++) {
    float4 b4 = *(const float4*)(bias + (jtbase + jt) * 16 + lgrp * 4);
#pragma unroll
    for (int it = 0; it < 4; it++) acc[jt][it] = (f32x4){b4.x, b4.y, b4.z, b4.w};
  }
#pragma unroll
  for (int ks = 0; ks < 4; ks++) {
    f16x8 awh[4], awl[4];
#pragma unroll
    for (int jt = 0; jt < 4; jt++) {
      size_t fo = (size_t)(((jtbase + jt) * 4 + ks) * 64 + lane) * 8;
      awh[jt] = *(const f16x8*)(slot + fo);
      awl[jt] = *(const f16x8*)(slot + fo + 16384);
    }
#pragma unroll
    for (int it = 0; it < 4; it++) {
      f16x8 bh = *(const f16x8*)(myt + (it * 16 + lrow) * TPH + ks * 32 + lgrp * 8);
#pragma unroll
      for (int jt = 0; jt < 4; jt++) {
        acc[jt][it] = __builtin_amdgcn_mfma_f32_16x16x32_f16(awh[jt], bh, acc[jt][it], 0, 0, 0);
        acc[jt][it] = __builtin_amdgcn_mfma_f32_16x16x32_f16(awl[jt], bh, acc[jt][it], 0, 0, 0);
      }
    }
  }
#pragma unroll
  for (int jt = 0; jt < 4; jt++)
#pragma unroll
    for (int it = 0; it < 4; it++)
#pragma unroll
      for (int c = 0; c < 4; c++) acc[jt][it][c] = fmaxf(acc[jt][it][c], 0.f);
  __syncthreads();  // all reads of e tile complete
#pragma unroll
  for (int it = 0; it < 4; it++)
#pragma unroll
    for (int jt = 0; jt < 4; jt++) {
      _Float16 o4[4];
#pragma unroll
      for (int c = 0; c < 4; c++) o4[c] = (_Float16)acc[jt][it][c];
      *(uint2*)(myt + (it * 16 + lrow) * TPH + (jtbase + jt) * 16 + lgrp * 4) = *(uint2*)o4;
    }
  __syncthreads();

  // ======== stage 3: p = l2norm(t @ W[9+2wh] + ph_bb)  (f16 hi/lo) ========
  slot = Wp + (size_t)(9 + 2 * wh) * 32768;
  bias = wh ? ph2_bb : ph1_bb;
#pragma unroll
  for (int jt = 0; jt < 4; jt++) {
    float4 b4 = *(const float4*)(bias + (jtbase + jt) * 16 + lgrp * 4);
#pragma unroll
    for (int it = 0; it < 4; it++) acc[jt][it] = (f32x4){b4.x, b4.y, b4.z, b4.w};
  }
#pragma unroll
  for (int ks = 0; ks < 4; ks++) {
    f16x8 awh[4], awl[4];
#pragma unroll
    for (int jt = 0; jt < 4; jt++) {
      size_t fo = (size_t)(((jtbase + jt) * 4 + ks) * 64 + lane) * 8;
      awh[jt] = *(const f16x8*)(slot + fo);
      awl[jt] = *(const f16x8*)(slot + fo + 16384);
    }
#pragma unroll
    for (int it = 0; it < 4; it++) {
      f16x8 bh = *(const f16x8*)(myt + (it * 16 + lrow) * TPH + ks * 32 + lgrp * 8);
#pragma unroll
      for (int jt = 0; jt < 4; jt++) {
        acc[jt][it] = __builtin_amdgcn_mfma_f32_16x16x32_f16(awh[jt], bh, acc[jt][it], 0, 0, 0);
        acc[jt][it] = __builtin_amdgcn_mfma_f32_16x16x32_f16(awl[jt], bh, acc[jt][it], 0, 0, 0);
      }
    }
  }
#pragma unroll
  for (int it = 0; it < 4; it++) {
    float rs = 0.f;
#pragma unroll
    for (int jt = 0; jt < 4; jt++)
#pragma unroll
      for (int c = 0; c < 4; c++) rs += acc[jt][it][c] * acc[jt][it][c];
    rs += __shfl_xor(rs, 16);
    rs += __shfl_xor(rs, 32);
    rsv[it] = rs;
    if (lane < 16) l2red[wh][it][lane][wj] = rs;
  }
  __syncthreads();
#pragma unroll
  for (int it = 0; it < 4; it++) {
    float full = rsv[it] + l2red[wh][it][lrow][wj ^ 1];
    float scl = 1.f / fmaxf(sqrtf(full), 1e-12f);
    if (!valid[it]) continue;
#pragma unroll
    for (int jt = 0; jt < 4; jt++)
      *(float4*)(out + (size_t)(2 + wh) * ND + (size_t)node[it] * 128 + (jtbase + jt) * 16 + lgrp * 4) =
          make_float4(acc[jt][it][0] * scl, acc[jt][it][1] * scl,
                      acc[jt][it][2] * scl, acc[jt][it][3] * scl);
  }
}

// ---------------- launch ----------------
extern "C" void kernel_launch(void* const* d_in, const int* in_sizes, int n_in,
                              void* d_out, int out_size, void* d_ws, size_t ws_size,
                              hipStream_t stream) {
  const float* x      = (const float*)d_in[0];
  const int*   ei0    = (const int*)d_in[1];
  const int*   ei1    = (const int*)d_in[2];
  const float* W0     = (const float*)d_in[3];
  const float* b0     = (const float*)d_in[4];
  const float* W1     = (const float*)d_in[5];
  const float* b1     = (const float*)d_in[6];
  const float* gamma  = (const float*)d_in[7];
  const float* beta   = (const float*)d_in[8];
  const float* emb1_W = (const float*)d_in[9];
  const float* emb1_b = (const float*)d_in[10];
  const float* emb2_W = (const float*)d_in[11];
  const float* emb2_b = (const float*)d_in[12];
  const float* ph1_Wa = (const float*)d_in[13];
  const float* ph1_ba = (const float*)d_in[14];
  const float* ph1_Wb = (const float*)d_in[15];
  const float* ph1_bb = (const float*)d_in[16];
  const float* ph2_Wa = (const float*)d_in[17];
  const float* ph2_ba = (const float*)d_in[18];
  const float* ph2_Wb = (const float*)d_in[19];
  const float* ph2_bb = (const float*)d_in[20];

  const int N = in_sizes[0] / D;
  const int E = in_sizes[1] / 2;
  const int N2 = 2 * N;
  const size_t ND = (size_t)N * D;
  const float invn = 1.0f / (float)N;
  float* out = (float*)d_out;

  char* p = (char*)d_ws;
  auto carve = [&](size_t bytes) -> void* {
    void* r = (void*)p;
    p += (bytes + 255) & ~(size_t)255;
    return r;
  };
  int*   cnt   = (int*)carve((size_t)N2 * 4);
  float* stats = (float*)carve((size_t)3 * 2048 * 4);   // [layer][2][8][128]
  size_t zbytes = (size_t)((char*)(stats + 3 * 2048) - (char*)cnt);
  int*   off   = (int*)carve((size_t)(N2 + 1) * 4);
  float* dinv  = (float*)carve((size_t)N2 * 4);
  int*   csr   = (int*)carve((size_t)2 * E * 4);
  int*   bsum  = (int*)carve(256 * 4);
  unsigned short* Wp = (unsigned short*)carve((size_t)12 * 32768 * 2);
  float* hbuf = (float*)carve(4 * ND);
  _Float16* tab0 = (_Float16*)carve(2 * ND);
  _Float16* tab1 = (_Float16*)carve(2 * ND);

  const int TPB = 256;
  const int packBlocks = 768;
  const int gridPC = packBlocks + (E + TPB - 1) / TPB;
  const int fillBlocks = (E + TPB - 1) / TPB;
  const int nbScan = (N2 + 511) / 512;
  const int gridDual = (N + 63) / 64;
  const int gridGath = (N + 15) / 16;
  const int gridH3 = (N + 63) / 64;

  WPtrs P;
  P.w[0] = W0;                     P.w[1] = W1;
  P.w[2] = W0 + (size_t)D * D;     P.w[3] = W1 + (size_t)D * D;
  P.w[4] = W0 + (size_t)2 * D * D; P.w[5] = W1 + (size_t)2 * D * D;
  P.w[6] = emb1_W; P.w[7] = emb2_W;
  P.w[8] = ph1_Wa; P.w[9] = ph1_Wb;
  P.w[10] = ph2_Wa; P.w[11] = ph2_Wb;

  hipMemsetAsync(cnt, 0, zbytes, stream);
  packcount_kernel<<<gridPC, TPB, 0, stream>>>(P, Wp, ei0 + E, ei1 + E, cnt, E, N, packBlocks);
  scan_part_kernel<<<nbScan, TPB, 0, stream>>>(cnt, off, bsum, N2);
  scan_bsum_kernel<<<1, TPB, 0, stream>>>(bsum, nbScan, off + N2);
  scan_add_kernel<<<nbScan, TPB, 0, stream>>>(off, bsum, cnt, dinv, N2);

  // fused CSR-fill + layer-0 matmul
  fillmm0_kernel<<<fillBlocks + gridDual, TPB, 0, stream>>>(
      ei0, ei1, off, cnt, csr, E, fillBlocks, Wp, x, dinv, tab0, tab1, N, N);
  gather_kernel<<<gridGath, TPB, 0, stream>>>(tab0, tab1, dinv, off, csr,
                                              b0, b1, hbuf, stats, N, N);
  for (int i = 1; i < 3; i++) {
    mm_dual_k<<<gridDual, TPB, 0, stream>>>(Wp + (size_t)(2 * i) * 32768, hbuf,
                                            stats + (size_t)(i - 1) * 2048,
                                            gamma + (i - 1) * D, beta + (i - 1) * D,
                                            dinv, tab0, tab1, N, N, invn);
    gather_kernel<<<gridGath, TPB, 0, stream>>>(tab0, tab1, dinv, off, csr,
                                                b0 + i * D, b1 + i * D, hbuf,
                                                stats + (size_t)i * 2048, N, N);
  }

  heads3_kernel<<<gridH3, TPB, 0, stream>>>(
      Wp, hbuf, stats + (size_t)2 * 2048, gamma + 2 * D, beta + 2 * D,
      emb1_b, emb2_b, ph1_ba, ph1_bb, ph2_ba, ph2_bb, out, N, invn);
}